// Round 12
// baseline (834.102 us; speedup 1.0000x reference)
//
#include <hip/hip_runtime.h>
#include <math.h>

typedef __attribute__((ext_vector_type(8))) short bf16x8;
typedef __attribute__((ext_vector_type(4))) short short4v;
typedef __attribute__((ext_vector_type(4))) float f32x4;

__device__ __forceinline__ short f2bf(float v) {
  union { float f; unsigned u; } x; x.f = v;
  unsigned r = x.u + 0x7fffu + ((x.u >> 16) & 1u);
  return (short)(r >> 16);
}

__device__ __forceinline__ float bf2f(unsigned short u) {
  union { unsigned u; float f; } x; x.u = ((unsigned)u) << 16;
  return x.f;
}

__device__ __forceinline__ void gld_lds16(const void* g, void* l) {
  __builtin_amdgcn_global_load_lds((const __attribute__((address_space(1))) void*)g,
                                   (__attribute__((address_space(3))) void*)l, 16, 0, 0);
}

// ---------------- mega prologue: embed + ALL weight transposes in one dispatch ----------------
__global__ __launch_bounds__(256) void prologue_kernel(
    const float* __restrict__ x, const float* __restrict__ W_in, const float* __restrict__ b_in,
    const float* __restrict__ pe, short* __restrict__ hbf,
    const float* __restrict__ Wq, const float* __restrict__ Wk, const float* __restrict__ Wv,
    const float* __restrict__ Wo, const float* __restrict__ W1, const float* __restrict__ W2,
    const float* __restrict__ Ws1, const float* __restrict__ Wout,
    short* __restrict__ qkvt, short* __restrict__ wot, short* __restrict__ w1t,
    short* __restrict__ w2t, short* __restrict__ ws1t, short* __restrict__ woutT) {
  __shared__ float t[32][33];
  const int tid = threadIdx.x;
  int idx = blockIdx.x;
  if (idx < 8192) {  // ---- embed: h_bf = bf16(x @ W_in + b_in + pe) ----
    int col = (idx & 1) * 256 + tid;
    int row = idx >> 1;
    int s = row & 511;
    float a = b_in[col] + pe[s * 512 + col];
    const float* xr = x + (size_t)row * 32;
#pragma unroll
    for (int k = 0; k < 32; k++) a += xr[k] * W_in[k * 512 + col];
    hbf[(size_t)row * 512 + col] = f2bf(a);
    return;
  }
  idx -= 8192;
  const float* src;
  short* dst;
  int R, C, cx, cy;
  if (idx < 4608) {  // qkv: 18 z x (16x16)
    int z = idx >> 8, rem = idx & 255;
    cx = rem & 15; cy = rem >> 4;
    int which = z / 6, l = z % 6;
    src = (which == 0 ? Wq : which == 1 ? Wk : Wv) + (size_t)l * 262144;
    dst = qkvt + (size_t)l * 786432 + (size_t)which * 262144;
    R = 512; C = 512;
  } else if (idx < 6144) {  // wo: 6 z x (16x16)
    int j = idx - 4608;
    int l = j >> 8, rem = j & 255;
    cx = rem & 15; cy = rem >> 4;
    src = Wo + (size_t)l * 262144; dst = wot + (size_t)l * 262144;
    R = 512; C = 512;
  } else if (idx < 12288) {  // w1: 6 z x (64x16)
    int j = idx - 6144;
    int l = j >> 10, rem = j & 1023;
    cx = rem & 63; cy = rem >> 6;
    src = W1 + (size_t)l * 1048576; dst = w1t + (size_t)l * 1048576;
    R = 512; C = 2048;
  } else if (idx < 18432) {  // w2: 6 z x (16x64)
    int j = idx - 12288;
    int l = j >> 10, rem = j & 1023;
    cx = rem & 15; cy = rem >> 4;
    src = W2 + (size_t)l * 1048576; dst = w2t + (size_t)l * 1048576;
    R = 2048; C = 512;
  } else if (idx < 18560) {  // ws1: (8x16)
    int j = idx - 18432;
    cx = j & 7; cy = j >> 3;
    src = Ws1; dst = ws1t; R = 512; C = 256;
  } else {  // wout: (1x16)
    int j = idx - 18560;
    cx = 0; cy = j;
    src = Wout; dst = woutT; R = 512; C = 32;
  }
  const int tx = tid & 31, ty = tid >> 5;
  const int c0 = cx * 32, r0 = cy * 32;
#pragma unroll
  for (int i = 0; i < 4; i++)
    t[ty + i * 8][tx] = src[(size_t)(r0 + ty + i * 8) * C + c0 + tx];
  __syncthreads();
#pragma unroll
  for (int i = 0; i < 4; i++)
    dst[(size_t)(c0 + ty + i * 8) * R + r0 + tx] = f2bf(t[tx][ty + i * 8]);
}

// ---------------- bf16 GEMM: A[M,K] x Bt[N,K]^T -> C[M,N] ----------------
// EPI: 2 bf16+bias+relu; 4 bf16+bias; 5 QKV: Q/K -> dense per-head qh, V -> Vt transposed
//      (V epilogue: 4 per-q values are consecutive in t at fixed dk -> one 8B short4 store)
// BK=32 only: 64B LDS row stride = 2-way bank alias (free, m136); BK=64 was 32-way (r4).
template <int EPI, int BM, int BN, int BK>
__global__ __launch_bounds__(256) void gemm_bt(const short* __restrict__ A,
                                               const short* __restrict__ Bt,
                                               short* __restrict__ Cb,
                                               short* __restrict__ Vt,
                                               const float* __restrict__ bias,
                                               int M, int N, int K) {
  __shared__ short As[BM * BK];
  __shared__ short Bs[BN * BK];
  const int tid = threadIdx.x;
  const int wid = tid >> 6;
  const int lane = tid & 63;
  const int m0 = blockIdx.y * BM;
  const int n0 = blockIdx.x * BN;
  constexpr int WR = BM / 2, WC = BN / 2, FI = WR / 16, FJ = WC / 16, KK = BK / 32;
  const int wr = (wid >> 1) * WR;
  const int wc = (wid & 1) * WC;

  f32x4 acc[FI][FJ];
#pragma unroll
  for (int i = 0; i < FI; i++)
#pragma unroll
    for (int j = 0; j < FJ; j++)
#pragma unroll
      for (int q = 0; q < 4; q++) acc[i][j][q] = 0.0f;

  const short* aBase = A + (size_t)m0 * K;
  const short* bBase = Bt + (size_t)n0 * K;
  constexpr int RPC = 512 / BK;
  constexpr int CA = BM / RPC;
  constexpr int CT = (BM + BN) / RPC;
  const int rowL = lane / (64 / RPC);
  const int colE = (lane % (64 / RPC)) * 8;
  const int kg = (lane >> 4) * 8;
  const int r16 = lane & 15;

  for (int kt = 0; kt < K; kt += BK) {
    __syncthreads();
#pragma unroll
    for (int c = 0; c < CT / 4; ++c) {
      int s = c * 4 + wid;
      if (s < CA)
        gld_lds16(aBase + (size_t)(s * RPC + rowL) * K + kt + colE, As + s * 512);
      else
        gld_lds16(bBase + (size_t)((s - CA) * RPC + rowL) * K + kt + colE, Bs + (s - CA) * 512);
    }
    __syncthreads();
    bf16x8 af[FI][KK], bfr[FJ][KK];
#pragma unroll
    for (int i = 0; i < FI; i++)
#pragma unroll
      for (int kk = 0; kk < KK; kk++)
        af[i][kk] = *(const bf16x8*)&As[(wr + i * 16 + r16) * BK + kk * 32 + kg];
#pragma unroll
    for (int j = 0; j < FJ; j++)
#pragma unroll
      for (int kk = 0; kk < KK; kk++)
        bfr[j][kk] = *(const bf16x8*)&Bs[(wc + j * 16 + r16) * BK + kk * 32 + kg];
#pragma unroll
    for (int kk = 0; kk < KK; kk++)
#pragma unroll
      for (int i = 0; i < FI; i++)
#pragma unroll
        for (int j = 0; j < FJ; j++)
          acc[i][j] = __builtin_amdgcn_mfma_f32_16x16x32_bf16(af[i][kk], bfr[j][kk], acc[i][j], 0, 0, 0);
  }

  const int col16 = lane & 15;
  const int rowg = (lane >> 4) * 4;
#pragma unroll
  for (int i = 0; i < FI; i++) {
    int row = m0 + wr + i * 16 + rowg;
#pragma unroll
    for (int j = 0; j < FJ; j++) {
      int col = n0 + wc + j * 16 + col16;
      if (EPI == 5) {
        int sect = col >> 9, hh = (col >> 6) & 7, dk = col & 63;
        int bq = row >> 9, tt = row & 511;  // same b for all q (128 | 512)
        if (sect < 2) {
#pragma unroll
          for (int q = 0; q < 4; q++)
            Cb[(((size_t)(sect * 64 + bq * 8 + hh)) * 512 + tt + q) * 64 + dk] =
                f2bf(acc[i][j][q]);
        } else {
          short4v pk;
#pragma unroll
          for (int q = 0; q < 4; q++) pk[q] = f2bf(acc[i][j][q]);
          *(short4v*)&Vt[((size_t)(bq * 8 + hh) * 64 + dk) * 512 + tt] = pk;
        }
      } else {
        float bv = bias[col];
#pragma unroll
        for (int q = 0; q < 4; q++) {
          float v = acc[i][j][q] + bv;
          if (EPI == 2) v = fmaxf(v, 0.0f);
          Cb[(size_t)(row + q) * N + col] = f2bf(v);
        }
      }
    }
  }
}

// ---------------- fused scores+softmax+P dump+PV: per (bh, 16-query tile) ----------------
// ~40us floor across 3 structures (r9-r11): per-wave serial work, not occupancy (35% Occ,
// all pipes <20%). PV uses dual accumulators to halve the dependent-MFMA chain.
__global__ __launch_bounds__(256) void smpv_kernel(const short* __restrict__ qh,
                                                   const short* __restrict__ Vt,
                                                   short* __restrict__ P,
                                                   short* __restrict__ ctxb) {
  __shared__ short Pl[16 * 512];  // 16KB, [q][t] bf16, swizzled byte^=(q&7)<<4
  __shared__ float red0[4][16];
  __shared__ float red1[4][16];
  const int bh = blockIdx.y, b = bh >> 3, h = bh & 7;
  const int q0 = blockIdx.x * 16;
  const int tid = threadIdx.x;
  const int wid = tid >> 6, lane = tid & 63;
  const int r16 = lane & 15, g = lane >> 4;

  const short* Qh = qh + ((size_t)bh * 512) * 64;
  const short* Kh = qh + ((size_t)(64 + bh) * 512) * 64;

  const short* qp = Qh + (size_t)(q0 + r16) * 64 + g * 8;
  const bf16x8 qa0 = *(const bf16x8*)qp;
  const bf16x8 qa1 = *(const bf16x8*)(qp + 32);

  f32x4 acc[8];
#pragma unroll
  for (int tt = 0; tt < 8; ++tt) {
    const short* kp = Kh + (size_t)(wid * 128 + tt * 16 + r16) * 64 + g * 8;
    bf16x8 kb0 = *(const bf16x8*)kp;
    bf16x8 kb1 = *(const bf16x8*)(kp + 32);
    f32x4 c = {0.f, 0.f, 0.f, 0.f};
    c = __builtin_amdgcn_mfma_f32_16x16x32_bf16(qa0, kb0, c, 0, 0, 0);
    c = __builtin_amdgcn_mfma_f32_16x16x32_bf16(qa1, kb1, c, 0, 0, 0);
    acc[tt] = c;
  }

  float mx[4] = {-1e30f, -1e30f, -1e30f, -1e30f};
#pragma unroll
  for (int tt = 0; tt < 8; ++tt)
#pragma unroll
    for (int r = 0; r < 4; ++r) mx[r] = fmaxf(mx[r], acc[tt][r]);
#pragma unroll
  for (int r = 0; r < 4; ++r)
#pragma unroll
    for (int m = 8; m; m >>= 1) mx[r] = fmaxf(mx[r], __shfl_xor(mx[r], m, 16));
  if (r16 == 0) {
#pragma unroll
    for (int r = 0; r < 4; ++r) red0[wid][g * 4 + r] = mx[r];
  }
  __syncthreads();
#pragma unroll
  for (int r = 0; r < 4; ++r) {
    int q = g * 4 + r;
    mx[r] = fmaxf(fmaxf(red0[0][q], red0[1][q]), fmaxf(red0[2][q], red0[3][q]));
  }
  float sum[4] = {0.f, 0.f, 0.f, 0.f};
#pragma unroll
  for (int tt = 0; tt < 8; ++tt)
#pragma unroll
    for (int r = 0; r < 4; ++r) {
      float e = __expf((acc[tt][r] - mx[r]) * 0.125f);
      acc[tt][r] = e;
      sum[r] += e;
    }
#pragma unroll
  for (int r = 0; r < 4; ++r)
#pragma unroll
    for (int m = 8; m; m >>= 1) sum[r] += __shfl_xor(sum[r], m, 16);
  if (r16 == 0) {
#pragma unroll
    for (int r = 0; r < 4; ++r) red1[wid][g * 4 + r] = sum[r];
  }
  __syncthreads();

  char* plc = (char*)Pl;
#pragma unroll
  for (int r = 0; r < 4; ++r) {
    int q = g * 4 + r;
    float inv = 1.0f / (red1[0][q] + red1[1][q] + red1[2][q] + red1[3][q]);
    int swz = (q & 7) << 4;
#pragma unroll
    for (int tt = 0; tt < 8; ++tt)
      *(short*)(plc + q * 1024 + (((wid * 128 + tt * 16 + r16) * 2) ^ swz)) =
          f2bf(acc[tt][r] * inv);
  }
  __syncthreads();

  short* pg = P + ((size_t)bh * 512 + q0) * 512;
#pragma unroll
  for (int k = 0; k < 4; ++k) {
    int c = k * 256 + tid;
    int q = c >> 6;
    int tB = (c & 63) * 16;
    bf16x8 v = *(const bf16x8*)(plc + q * 1024 + (tB ^ ((q & 7) << 4)));
    *(bf16x8*)&pg[(size_t)q * 512 + (c & 63) * 8] = v;
  }

  // PV: dual accumulators break the 16-deep dependent MFMA chain into 2x8
  f32x4 pacc0 = {0.f, 0.f, 0.f, 0.f}, pacc1 = {0.f, 0.f, 0.f, 0.f};
  const short* vb = Vt + (size_t)bh * 64 * 512 + (size_t)(wid * 16) * 512;
  const int rswz = (r16 & 7) << 4;
  for (int kt = 0; kt < 512; kt += 64) {
    bf16x8 af0 = *(const bf16x8*)(plc + r16 * 1024 + (((kt + g * 8) * 2) ^ rswz));
    bf16x8 af1 = *(const bf16x8*)(plc + r16 * 1024 + (((kt + 32 + g * 8) * 2) ^ rswz));
    bf16x8 b0 = *(const bf16x8*)&vb[(size_t)r16 * 512 + kt + g * 8];
    bf16x8 b1 = *(const bf16x8*)&vb[(size_t)r16 * 512 + kt + 32 + g * 8];
    pacc0 = __builtin_amdgcn_mfma_f32_16x16x32_bf16(af0, b0, pacc0, 0, 0, 0);
    pacc1 = __builtin_amdgcn_mfma_f32_16x16x32_bf16(af1, b1, pacc1, 0, 0, 0);
  }
  const int col = h * 64 + wid * 16 + r16;
#pragma unroll
  for (int q = 0; q < 4; ++q)
    ctxb[(size_t)(b * 512 + q0 + g * 4 + q) * 512 + col] = f2bf(pacc0[q] + pacc1[q]);
}

// ---------------- grid-union: Wo 64x64 GEMM (x<8) + KL head-sum (x>=8) ----------------
template <int FIRST>
__global__ __launch_bounds__(256) void wo_kl_kernel(const short* __restrict__ A,
                                                    const short* __restrict__ Bt,
                                                    const float* __restrict__ bias,
                                                    short* __restrict__ aout,
                                                    const short* __restrict__ P,
                                                    float* __restrict__ assoc) {
  __shared__ short As[64 * 32];
  __shared__ short Bs[64 * 32];
  const int tid = threadIdx.x;
  const int wid = tid >> 6, lane = tid & 63;
  if (blockIdx.x < 8) {
    const int m0 = blockIdx.y * 64;
    const int n0 = blockIdx.x * 64;
    const int wr = (wid >> 1) * 32;
    const int wc = (wid & 1) * 32;
    f32x4 acc[2][2];
#pragma unroll
    for (int i = 0; i < 2; i++)
#pragma unroll
      for (int j = 0; j < 2; j++)
#pragma unroll
        for (int q = 0; q < 4; q++) acc[i][j][q] = 0.0f;
    const short* aBase = A + (size_t)m0 * 512;
    const short* bBase = Bt + (size_t)n0 * 512;
    const int rowL = lane >> 2;
    const int colE = (lane & 3) * 8;
    const int kg = (lane >> 4) * 8;
    const int r16 = lane & 15;
    for (int kt = 0; kt < 512; kt += 32) {
      __syncthreads();
#pragma unroll
      for (int c = 0; c < 2; ++c) {
        int s = c * 4 + wid;
        if (s < 4)
          gld_lds16(aBase + (size_t)(s * 16 + rowL) * 512 + kt + colE, As + s * 512);
        else
          gld_lds16(bBase + (size_t)((s - 4) * 16 + rowL) * 512 + kt + colE, Bs + (s - 4) * 512);
      }
      __syncthreads();
      bf16x8 af[2], bfr[2];
#pragma unroll
      for (int i = 0; i < 2; i++)
        af[i] = *(const bf16x8*)&As[(wr + i * 16 + r16) * 32 + kg];
#pragma unroll
      for (int j = 0; j < 2; j++)
        bfr[j] = *(const bf16x8*)&Bs[(wc + j * 16 + r16) * 32 + kg];
#pragma unroll
      for (int i = 0; i < 2; i++)
#pragma unroll
        for (int j = 0; j < 2; j++)
          acc[i][j] = __builtin_amdgcn_mfma_f32_16x16x32_bf16(af[i], bfr[j], acc[i][j], 0, 0, 0);
    }
    const int col16 = lane & 15;
    const int rowg = (lane >> 4) * 4;
#pragma unroll
    for (int i = 0; i < 2; i++) {
      int row = m0 + wr + i * 16 + rowg;
#pragma unroll
      for (int j = 0; j < 2; j++) {
        int col = n0 + wc + j * 16 + col16;
        float bv = bias[col];
#pragma unroll
        for (int q = 0; q < 4; q++)
          aout[(size_t)(row + q) * 512 + col] = f2bf(acc[i][j][q] + bv);
      }
    }
  } else {
    const int kb = (blockIdx.x - 8) * 64 + blockIdx.y;
    const int row = kb * 4 + wid;
    const int b = row >> 9, q = row & 511;
    const float prior = 1.0f / 512.0f + 1e-8f;
    float hs[8] = {0.f, 0.f, 0.f, 0.f, 0.f, 0.f, 0.f, 0.f};
#pragma unroll
    for (int h = 0; h < 8; ++h) {
      bf16x8 v = *(const bf16x8*)&P[(((size_t)(b * 8 + h)) * 512 + q) * 512 + lane * 8];
#pragma unroll
      for (int k = 0; k < 8; ++k) hs[k] += bf2f((unsigned short)v[k]);
    }
    float s = 0.f;
#pragma unroll
    for (int k = 0; k < 8; ++k) {
      float a = hs[k] * 0.125f + 1e-8f;
      s += a * __logf(a / prior);
    }
#pragma unroll
    for (int m = 32; m; m >>= 1) s += __shfl_xor(s, m, 64);
    if (lane == 0) assoc[row] = FIRST ? s : (assoc[row] + s);
  }
}

// ---------------- layernorm in-place on bf16 residual stream ----------------
__global__ __launch_bounds__(256) void ln_kernel(const short* __restrict__ res,
                                                 const float* __restrict__ g,
                                                 const float* __restrict__ bta,
                                                 short* __restrict__ hbf) {
  const int wid = threadIdx.x >> 6, lane = threadIdx.x & 63;
  const size_t row = (size_t)blockIdx.x * 4 + wid;
  bf16x8 hv = *(const bf16x8*)&hbf[row * 512 + lane * 8];
  bf16x8 rv = *(const bf16x8*)&res[row * 512 + lane * 8];
  float v[8], s = 0.f, s2 = 0.f;
#pragma unroll
  for (int i = 0; i < 8; i++) {
    v[i] = bf2f((unsigned short)hv[i]) + bf2f((unsigned short)rv[i]);
    s += v[i];
    s2 += v[i] * v[i];
  }
#pragma unroll
  for (int m = 32; m; m >>= 1) {
    s += __shfl_xor(s, m, 64);
    s2 += __shfl_xor(s2, m, 64);
  }
  float mu = s * (1.0f / 512.0f);
  float var = s2 * (1.0f / 512.0f) - mu * mu;
  float rs = rsqrtf(var + 1e-5f);
  const float* gp = g + lane * 8;
  const float* bp = bta + lane * 8;
  bf16x8 ob;
#pragma unroll
  for (int i = 0; i < 8; i++) ob[i] = f2bf((v[i] - mu) * rs * gp[i] + bp[i]);
  *(bf16x8*)&hbf[row * 512 + lane * 8] = ob;
}

// ---------------- reconstruction via MFMA: out[4096,32] = h_bf @ WoutT^T + bout ----------------
__global__ __launch_bounds__(256) void recon_mfma(const short* __restrict__ hbf,
                                                  const short* __restrict__ WoutT,
                                                  const float* __restrict__ bout,
                                                  float* __restrict__ out) {
  const int wid = threadIdx.x >> 6, lane = threadIdx.x & 63;
  const int r16 = lane & 15, kg = (lane >> 4) * 8;
  const int wbase = blockIdx.x * 128 + wid * 32;

  f32x4 acc[2][2];
#pragma unroll
  for (int i = 0; i < 2; i++)
#pragma unroll
    for (int j = 0; j < 2; j++)
#pragma unroll
      for (int q = 0; q < 4; q++) acc[i][j][q] = 0.0f;

  for (int kt = 0; kt < 512; kt += 32) {
    bf16x8 af[2], bfr[2];
#pragma unroll
    for (int i = 0; i < 2; i++)
      af[i] = *(const bf16x8*)&hbf[(size_t)(wbase + i * 16 + r16) * 512 + kt + kg];
#pragma unroll
    for (int j = 0; j < 2; j++)
      bfr[j] = *(const bf16x8*)&WoutT[(size_t)(j * 16 + r16) * 512 + kt + kg];
#pragma unroll
    for (int i = 0; i < 2; i++)
#pragma unroll
      for (int j = 0; j < 2; j++)
        acc[i][j] = __builtin_amdgcn_mfma_f32_16x16x32_bf16(af[i], bfr[j], acc[i][j], 0, 0, 0);
  }

  const int rowg = (lane >> 4) * 4;
#pragma unroll
  for (int i = 0; i < 2; i++)
#pragma unroll
    for (int j = 0; j < 2; j++) {
      int col = j * 16 + r16;
#pragma unroll
      for (int q = 0; q < 4; q++)
        out[(size_t)(wbase + i * 16 + rowg + q) * 32 + col] = acc[i][j][q] + bout[col];
    }
}

// ---------------- score stage 2 + assoc output ----------------
__global__ __launch_bounds__(256) void score2_kernel(const short* __restrict__ s1,
                                                     const float* __restrict__ Ws2,
                                                     const float* __restrict__ bs2,
                                                     const float* __restrict__ assoc,
                                                     float* __restrict__ outScore,
                                                     float* __restrict__ outAssoc) {
  const int wid = threadIdx.x >> 6, lane = threadIdx.x & 63;
  const int row = blockIdx.x * 4 + wid;
  const short* rp = &s1[(size_t)row * 256 + lane * 4];
  float d = 0.f;
#pragma unroll
  for (int e = 0; e < 4; e++) d += bf2f((unsigned short)rp[e]) * Ws2[lane * 4 + e];
#pragma unroll
  for (int m = 32; m; m >>= 1) d += __shfl_xor(d, m, 64);
  if (lane == 0) {
    outScore[row] = 1.f / (1.f + __expf(-(d + bs2[0])));
    outAssoc[row] = assoc[row] * (1.0f / 6.0f);
  }
}

extern "C" void kernel_launch(void* const* d_in, const int* in_sizes, int n_in,
                              void* d_out, int out_size, void* d_ws, size_t ws_size,
                              hipStream_t stream) {
  const float* x    = (const float*)d_in[0];
  const float* W_in = (const float*)d_in[1];
  const float* b_in = (const float*)d_in[2];
  const float* pe   = (const float*)d_in[3];
  const float* Wq   = (const float*)d_in[4];
  const float* Wk   = (const float*)d_in[5];
  const float* Wv   = (const float*)d_in[6];
  const float* Wo   = (const float*)d_in[7];
  const float* bo   = (const float*)d_in[8];
  const float* W1   = (const float*)d_in[9];
  const float* b1   = (const float*)d_in[10];
  const float* W2   = (const float*)d_in[11];
  const float* b2   = (const float*)d_in[12];
  const float* ln1g = (const float*)d_in[13];
  const float* ln1b = (const float*)d_in[14];
  const float* ln2g = (const float*)d_in[15];
  const float* ln2b = (const float*)d_in[16];
  const float* Wout = (const float*)d_in[17];
  const float* bout = (const float*)d_in[18];
  const float* Ws1  = (const float*)d_in[19];
  const float* bs1  = (const float*)d_in[20];
  const float* Ws2  = (const float*)d_in[21];
  const float* bs2  = (const float*)d_in[22];

  char* p = (char*)d_ws;
  auto alloc = [&](size_t bytes) {
    void* r = (void*)p;
    p += (bytes + 255) & ~(size_t)255;
    return r;
  };
  short* h_bf  = (short*)alloc((size_t)4096 * 512 * 2);
  short* qh    = (short*)alloc((size_t)4096 * 1536 * 2);
  short* aout  = (short*)alloc((size_t)4096 * 512 * 2);
  short* ctxb  = (short*)alloc((size_t)4096 * 512 * 2);
  short* ff1b  = (short*)alloc((size_t)4096 * 2048 * 2);
  short* ff2   = (short*)alloc((size_t)4096 * 512 * 2);
  float* assoc = (float*)alloc((size_t)4096 * 4);
  short* Pbuf  = (short*)alloc((size_t)64 * 512 * 512 * 2);
  short* Vt    = (short*)alloc((size_t)64 * 64 * 512 * 2);
  short* sc1   = (short*)alloc((size_t)4096 * 256 * 2);
  short* qkvt  = (short*)alloc((size_t)6 * 1536 * 512 * 2);
  short* wot   = (short*)alloc((size_t)6 * 512 * 512 * 2);
  short* w1t   = (short*)alloc((size_t)6 * 2048 * 512 * 2);
  short* w2t   = (short*)alloc((size_t)6 * 512 * 2048 * 2);
  short* ws1t  = (short*)alloc((size_t)256 * 512 * 2);
  short* woutT = (short*)alloc((size_t)32 * 512 * 2);

  prologue_kernel<<<26768, 256, 0, stream>>>(x, W_in, b_in, pe, h_bf, Wq, Wk, Wv, Wo, W1, W2,
                                             Ws1, Wout, qkvt, wot, w1t, w2t, ws1t, woutT);

  for (int l = 0; l < 6; ++l) {
    gemm_bt<5, 128, 128, 32><<<dim3(12, 32), 256, 0, stream>>>(
        h_bf, qkvt + (size_t)l * 786432, qh, Vt, nullptr, 4096, 1536, 512);
    smpv_kernel<<<dim3(32, 64), 256, 0, stream>>>(qh, Vt, Pbuf, ctxb);
    if (l == 0)
      wo_kl_kernel<1><<<dim3(24, 64), 256, 0, stream>>>(ctxb, wot + (size_t)l * 262144,
                                                        bo + l * 512, aout, Pbuf, assoc);
    else
      wo_kl_kernel<0><<<dim3(24, 64), 256, 0, stream>>>(ctxb, wot + (size_t)l * 262144,
                                                        bo + l * 512, aout, Pbuf, assoc);
    ln_kernel<<<1024, 256, 0, stream>>>(aout, ln1g + l * 512, ln1b + l * 512, h_bf);
    gemm_bt<2, 128, 128, 32><<<dim3(16, 32), 256, 0, stream>>>(
        h_bf, w1t + (size_t)l * 1048576, ff1b, nullptr, b1 + l * 2048, 4096, 2048, 512);
    gemm_bt<4, 128, 64, 32><<<dim3(8, 32), 256, 0, stream>>>(
        ff1b, w2t + (size_t)l * 1048576, ff2, nullptr, b2 + l * 512, 4096, 512, 2048);
    ln_kernel<<<1024, 256, 0, stream>>>(ff2, ln2g + l * 512, ln2b + l * 512, h_bf);
  }

  float* out = (float*)d_out;
  recon_mfma<<<32, 256, 0, stream>>>(h_bf, woutT, bout, out);
  gemm_bt<2, 128, 128, 32><<<dim3(2, 32), 256, 0, stream>>>(h_bf, ws1t, sc1, nullptr, bs1,
                                                            4096, 256, 512);
  score2_kernel<<<1024, 256, 0, stream>>>(sc1, Ws2, bs2, assoc, out + 131072,
                                          out + 131072 + 4096);
}

// Round 13
// 797.116 us; speedup vs baseline: 1.0464x; 1.0464x over previous
//
#include <hip/hip_runtime.h>
#include <math.h>

typedef __attribute__((ext_vector_type(8))) short bf16x8;
typedef __attribute__((ext_vector_type(4))) float f32x4;

__device__ __forceinline__ short f2bf(float v) {
  union { float f; unsigned u; } x; x.f = v;
  unsigned r = x.u + 0x7fffu + ((x.u >> 16) & 1u);
  return (short)(r >> 16);
}

__device__ __forceinline__ float bf2f(unsigned short u) {
  union { unsigned u; float f; } x; x.u = ((unsigned)u) << 16;
  return x.f;
}

__device__ __forceinline__ void gld_lds16(const void* g, void* l) {
  __builtin_amdgcn_global_load_lds((const __attribute__((address_space(1))) void*)g,
                                   (__attribute__((address_space(3))) void*)l, 16, 0, 0);
}

// ---------------- mega prologue: embed + ALL weight transposes in one dispatch ----------------
__global__ __launch_bounds__(256) void prologue_kernel(
    const float* __restrict__ x, const float* __restrict__ W_in, const float* __restrict__ b_in,
    const float* __restrict__ pe, short* __restrict__ hbf,
    const float* __restrict__ Wq, const float* __restrict__ Wk, const float* __restrict__ Wv,
    const float* __restrict__ Wo, const float* __restrict__ W1, const float* __restrict__ W2,
    const float* __restrict__ Ws1, const float* __restrict__ Wout,
    short* __restrict__ qkvt, short* __restrict__ wot, short* __restrict__ w1t,
    short* __restrict__ w2t, short* __restrict__ ws1t, short* __restrict__ woutT) {
  __shared__ float t[32][33];
  const int tid = threadIdx.x;
  int idx = blockIdx.x;
  if (idx < 8192) {  // ---- embed: h_bf = bf16(x @ W_in + b_in + pe) ----
    int col = (idx & 1) * 256 + tid;
    int row = idx >> 1;
    int s = row & 511;
    float a = b_in[col] + pe[s * 512 + col];
    const float* xr = x + (size_t)row * 32;
#pragma unroll
    for (int k = 0; k < 32; k++) a += xr[k] * W_in[k * 512 + col];
    hbf[(size_t)row * 512 + col] = f2bf(a);
    return;
  }
  idx -= 8192;
  const float* src;
  short* dst;
  int R, C, cx, cy;
  if (idx < 4608) {  // qkv: 18 z x (16x16)
    int z = idx >> 8, rem = idx & 255;
    cx = rem & 15; cy = rem >> 4;
    int which = z / 6, l = z % 6;
    src = (which == 0 ? Wq : which == 1 ? Wk : Wv) + (size_t)l * 262144;
    dst = qkvt + (size_t)l * 786432 + (size_t)which * 262144;
    R = 512; C = 512;
  } else if (idx < 6144) {  // wo: 6 z x (16x16)
    int j = idx - 4608;
    int l = j >> 8, rem = j & 255;
    cx = rem & 15; cy = rem >> 4;
    src = Wo + (size_t)l * 262144; dst = wot + (size_t)l * 262144;
    R = 512; C = 512;
  } else if (idx < 12288) {  // w1: 6 z x (64x16)
    int j = idx - 6144;
    int l = j >> 10, rem = j & 1023;
    cx = rem & 63; cy = rem >> 6;
    src = W1 + (size_t)l * 1048576; dst = w1t + (size_t)l * 1048576;
    R = 512; C = 2048;
  } else if (idx < 18432) {  // w2: 6 z x (16x64)
    int j = idx - 12288;
    int l = j >> 10, rem = j & 1023;
    cx = rem & 15; cy = rem >> 4;
    src = W2 + (size_t)l * 1048576; dst = w2t + (size_t)l * 1048576;
    R = 2048; C = 512;
  } else if (idx < 18560) {  // ws1: (8x16)
    int j = idx - 18432;
    cx = j & 7; cy = j >> 3;
    src = Ws1; dst = ws1t; R = 512; C = 256;
  } else {  // wout: (1x16)
    int j = idx - 18560;
    cx = 0; cy = j;
    src = Wout; dst = woutT; R = 512; C = 32;
  }
  const int tx = tid & 31, ty = tid >> 5;
  const int c0 = cx * 32, r0 = cy * 32;
#pragma unroll
  for (int i = 0; i < 4; i++)
    t[ty + i * 8][tx] = src[(size_t)(r0 + ty + i * 8) * C + c0 + tx];
  __syncthreads();
#pragma unroll
  for (int i = 0; i < 4; i++)
    dst[(size_t)(c0 + ty + i * 8) * R + r0 + tx] = f2bf(t[tx][ty + i * 8]);
}

// ---------------- bf16 GEMM: A[M,K] x Bt[N,K]^T -> C[M,N] ----------------
// EPI: 2 bf16+bias+relu; 4 bf16+bias; 5 bf16 QKV->dense per-head layout (coalesced)
// BK=32 only: 64B LDS row stride = 2-way bank alias (free, m136); BK=64 was 32-way (r4).
// r12 lessons: V-transpose in this epilogue = 8B stores 1KB apart (12.5% line util) -> keep
// vt_kernel; FF2 at 128x64 = 256 blocks = 1 blk/CU, no TLP -> keep 64x64 grid 512.
template <int EPI, int BM, int BN, int BK>
__global__ __launch_bounds__(256) void gemm_bt(const short* __restrict__ A,
                                               const short* __restrict__ Bt,
                                               short* __restrict__ Cb,
                                               const float* __restrict__ bias,
                                               int M, int N, int K) {
  __shared__ short As[BM * BK];
  __shared__ short Bs[BN * BK];
  const int tid = threadIdx.x;
  const int wid = tid >> 6;
  const int lane = tid & 63;
  const int m0 = blockIdx.y * BM;
  const int n0 = blockIdx.x * BN;
  constexpr int WR = BM / 2, WC = BN / 2, FI = WR / 16, FJ = WC / 16, KK = BK / 32;
  const int wr = (wid >> 1) * WR;
  const int wc = (wid & 1) * WC;

  f32x4 acc[FI][FJ];
#pragma unroll
  for (int i = 0; i < FI; i++)
#pragma unroll
    for (int j = 0; j < FJ; j++)
#pragma unroll
      for (int q = 0; q < 4; q++) acc[i][j][q] = 0.0f;

  const short* aBase = A + (size_t)m0 * K;
  const short* bBase = Bt + (size_t)n0 * K;
  constexpr int RPC = 512 / BK;
  constexpr int CA = BM / RPC;
  constexpr int CT = (BM + BN) / RPC;
  const int rowL = lane / (64 / RPC);
  const int colE = (lane % (64 / RPC)) * 8;
  const int kg = (lane >> 4) * 8;
  const int r16 = lane & 15;

  for (int kt = 0; kt < K; kt += BK) {
    __syncthreads();
#pragma unroll
    for (int c = 0; c < CT / 4; ++c) {
      int s = c * 4 + wid;
      if (s < CA)
        gld_lds16(aBase + (size_t)(s * RPC + rowL) * K + kt + colE, As + s * 512);
      else
        gld_lds16(bBase + (size_t)((s - CA) * RPC + rowL) * K + kt + colE, Bs + (s - CA) * 512);
    }
    __syncthreads();
    bf16x8 af[FI][KK], bfr[FJ][KK];
#pragma unroll
    for (int i = 0; i < FI; i++)
#pragma unroll
      for (int kk = 0; kk < KK; kk++)
        af[i][kk] = *(const bf16x8*)&As[(wr + i * 16 + r16) * BK + kk * 32 + kg];
#pragma unroll
    for (int j = 0; j < FJ; j++)
#pragma unroll
      for (int kk = 0; kk < KK; kk++)
        bfr[j][kk] = *(const bf16x8*)&Bs[(wc + j * 16 + r16) * BK + kk * 32 + kg];
#pragma unroll
    for (int kk = 0; kk < KK; kk++)
#pragma unroll
      for (int i = 0; i < FI; i++)
#pragma unroll
        for (int j = 0; j < FJ; j++)
          acc[i][j] = __builtin_amdgcn_mfma_f32_16x16x32_bf16(af[i][kk], bfr[j][kk], acc[i][j], 0, 0, 0);
  }

  const int col16 = lane & 15;
  const int rowg = (lane >> 4) * 4;
#pragma unroll
  for (int i = 0; i < FI; i++) {
    int row = m0 + wr + i * 16 + rowg;
#pragma unroll
    for (int j = 0; j < FJ; j++) {
      int col = n0 + wc + j * 16 + col16;
      float bv = (EPI == 2 || EPI == 4) ? bias[col] : 0.0f;
#pragma unroll
      for (int q = 0; q < 4; q++) {
        float v = acc[i][j][q] + bv;
        if (EPI == 2) {
          v = fmaxf(v, 0.0f);
          Cb[(size_t)(row + q) * N + col] = f2bf(v);
        } else if (EPI == 5) {
          int rr = row + q;
          int sect = col >> 9, hh = (col >> 6) & 7, dk = col & 63;
          int bq = rr >> 9, tt = rr & 511;
          Cb[(((size_t)(sect * 64 + bq * 8 + hh)) * 512 + tt) * 64 + dk] = f2bf(v);
        } else {
          Cb[(size_t)(row + q) * N + col] = f2bf(v);
        }
      }
    }
  }
}

// ---------------- V transpose (dense layout): qh V-section -> Vt[bh][64 dk][512 t] ----------------
__global__ __launch_bounds__(256) void vt_kernel(const short* __restrict__ qh,
                                                 short* __restrict__ Vt) {
  __shared__ short t[32][34];
  const int bh = blockIdx.z;
  const int t0 = blockIdx.x * 32, d0 = blockIdx.y * 32;
  const int tx = threadIdx.x & 31, ty = threadIdx.x >> 5;
  const short* Vh = qh + (size_t)(128 + bh) * 512 * 64;
#pragma unroll
  for (int i = 0; i < 4; i++)
    t[ty + i * 8][tx] = Vh[(size_t)(t0 + ty + i * 8) * 64 + d0 + tx];
  __syncthreads();
#pragma unroll
  for (int i = 0; i < 4; i++)
    Vt[((size_t)bh * 64 + d0 + ty + i * 8) * 512 + t0 + tx] = t[tx][ty + i * 8];
}

// ---------------- fused scores+softmax+P dump+PV: per (bh, 16-query tile) ----------------
// ~40us floor across 3 structures (r9-r11): per-wave serial work, not occupancy (35% Occ,
// all pipes <20%). PV uses dual accumulators to halve the dependent-MFMA chain.
__global__ __launch_bounds__(256) void smpv_kernel(const short* __restrict__ qh,
                                                   const short* __restrict__ Vt,
                                                   short* __restrict__ P,
                                                   short* __restrict__ ctxb) {
  __shared__ short Pl[16 * 512];  // 16KB, [q][t] bf16, swizzled byte^=(q&7)<<4
  __shared__ float red0[4][16];
  __shared__ float red1[4][16];
  const int bh = blockIdx.y, b = bh >> 3, h = bh & 7;
  const int q0 = blockIdx.x * 16;
  const int tid = threadIdx.x;
  const int wid = tid >> 6, lane = tid & 63;
  const int r16 = lane & 15, g = lane >> 4;

  const short* Qh = qh + ((size_t)bh * 512) * 64;
  const short* Kh = qh + ((size_t)(64 + bh) * 512) * 64;

  const short* qp = Qh + (size_t)(q0 + r16) * 64 + g * 8;
  const bf16x8 qa0 = *(const bf16x8*)qp;
  const bf16x8 qa1 = *(const bf16x8*)(qp + 32);

  f32x4 acc[8];
#pragma unroll
  for (int tt = 0; tt < 8; ++tt) {
    const short* kp = Kh + (size_t)(wid * 128 + tt * 16 + r16) * 64 + g * 8;
    bf16x8 kb0 = *(const bf16x8*)kp;
    bf16x8 kb1 = *(const bf16x8*)(kp + 32);
    f32x4 c = {0.f, 0.f, 0.f, 0.f};
    c = __builtin_amdgcn_mfma_f32_16x16x32_bf16(qa0, kb0, c, 0, 0, 0);
    c = __builtin_amdgcn_mfma_f32_16x16x32_bf16(qa1, kb1, c, 0, 0, 0);
    acc[tt] = c;
  }

  float mx[4] = {-1e30f, -1e30f, -1e30f, -1e30f};
#pragma unroll
  for (int tt = 0; tt < 8; ++tt)
#pragma unroll
    for (int r = 0; r < 4; ++r) mx[r] = fmaxf(mx[r], acc[tt][r]);
#pragma unroll
  for (int r = 0; r < 4; ++r)
#pragma unroll
    for (int m = 8; m; m >>= 1) mx[r] = fmaxf(mx[r], __shfl_xor(mx[r], m, 16));
  if (r16 == 0) {
#pragma unroll
    for (int r = 0; r < 4; ++r) red0[wid][g * 4 + r] = mx[r];
  }
  __syncthreads();
#pragma unroll
  for (int r = 0; r < 4; ++r) {
    int q = g * 4 + r;
    mx[r] = fmaxf(fmaxf(red0[0][q], red0[1][q]), fmaxf(red0[2][q], red0[3][q]));
  }
  float sum[4] = {0.f, 0.f, 0.f, 0.f};
#pragma unroll
  for (int tt = 0; tt < 8; ++tt)
#pragma unroll
    for (int r = 0; r < 4; ++r) {
      float e = __expf((acc[tt][r] - mx[r]) * 0.125f);
      acc[tt][r] = e;
      sum[r] += e;
    }
#pragma unroll
  for (int r = 0; r < 4; ++r)
#pragma unroll
    for (int m = 8; m; m >>= 1) sum[r] += __shfl_xor(sum[r], m, 16);
  if (r16 == 0) {
#pragma unroll
    for (int r = 0; r < 4; ++r) red1[wid][g * 4 + r] = sum[r];
  }
  __syncthreads();

  char* plc = (char*)Pl;
#pragma unroll
  for (int r = 0; r < 4; ++r) {
    int q = g * 4 + r;
    float inv = 1.0f / (red1[0][q] + red1[1][q] + red1[2][q] + red1[3][q]);
    int swz = (q & 7) << 4;
#pragma unroll
    for (int tt = 0; tt < 8; ++tt)
      *(short*)(plc + q * 1024 + (((wid * 128 + tt * 16 + r16) * 2) ^ swz)) =
          f2bf(acc[tt][r] * inv);
  }
  __syncthreads();

  short* pg = P + ((size_t)bh * 512 + q0) * 512;
#pragma unroll
  for (int k = 0; k < 4; ++k) {
    int c = k * 256 + tid;
    int q = c >> 6;
    int tB = (c & 63) * 16;
    bf16x8 v = *(const bf16x8*)(plc + q * 1024 + (tB ^ ((q & 7) << 4)));
    *(bf16x8*)&pg[(size_t)q * 512 + (c & 63) * 8] = v;
  }

  // PV: dual accumulators break the 16-deep dependent MFMA chain into 2x8
  f32x4 pacc0 = {0.f, 0.f, 0.f, 0.f}, pacc1 = {0.f, 0.f, 0.f, 0.f};
  const short* vb = Vt + (size_t)bh * 64 * 512 + (size_t)(wid * 16) * 512;
  const int rswz = (r16 & 7) << 4;
  for (int kt = 0; kt < 512; kt += 64) {
    bf16x8 af0 = *(const bf16x8*)(plc + r16 * 1024 + (((kt + g * 8) * 2) ^ rswz));
    bf16x8 af1 = *(const bf16x8*)(plc + r16 * 1024 + (((kt + 32 + g * 8) * 2) ^ rswz));
    bf16x8 b0 = *(const bf16x8*)&vb[(size_t)r16 * 512 + kt + g * 8];
    bf16x8 b1 = *(const bf16x8*)&vb[(size_t)r16 * 512 + kt + 32 + g * 8];
    pacc0 = __builtin_amdgcn_mfma_f32_16x16x32_bf16(af0, b0, pacc0, 0, 0, 0);
    pacc1 = __builtin_amdgcn_mfma_f32_16x16x32_bf16(af1, b1, pacc1, 0, 0, 0);
  }
  const int col = h * 64 + wid * 16 + r16;
#pragma unroll
  for (int q = 0; q < 4; ++q)
    ctxb[(size_t)(b * 512 + q0 + g * 4 + q) * 512 + col] = f2bf(pacc0[q] + pacc1[q]);
}

// ---------------- grid-union: Wo 64x64 GEMM (x<8) + KL head-sum (x>=8) ----------------
template <int FIRST>
__global__ __launch_bounds__(256) void wo_kl_kernel(const short* __restrict__ A,
                                                    const short* __restrict__ Bt,
                                                    const float* __restrict__ bias,
                                                    short* __restrict__ aout,
                                                    const short* __restrict__ P,
                                                    float* __restrict__ assoc) {
  __shared__ short As[64 * 32];
  __shared__ short Bs[64 * 32];
  const int tid = threadIdx.x;
  const int wid = tid >> 6, lane = tid & 63;
  if (blockIdx.x < 8) {
    const int m0 = blockIdx.y * 64;
    const int n0 = blockIdx.x * 64;
    const int wr = (wid >> 1) * 32;
    const int wc = (wid & 1) * 32;
    f32x4 acc[2][2];
#pragma unroll
    for (int i = 0; i < 2; i++)
#pragma unroll
      for (int j = 0; j < 2; j++)
#pragma unroll
        for (int q = 0; q < 4; q++) acc[i][j][q] = 0.0f;
    const short* aBase = A + (size_t)m0 * 512;
    const short* bBase = Bt + (size_t)n0 * 512;
    const int rowL = lane >> 2;
    const int colE = (lane & 3) * 8;
    const int kg = (lane >> 4) * 8;
    const int r16 = lane & 15;
    for (int kt = 0; kt < 512; kt += 32) {
      __syncthreads();
#pragma unroll
      for (int c = 0; c < 2; ++c) {
        int s = c * 4 + wid;
        if (s < 4)
          gld_lds16(aBase + (size_t)(s * 16 + rowL) * 512 + kt + colE, As + s * 512);
        else
          gld_lds16(bBase + (size_t)((s - 4) * 16 + rowL) * 512 + kt + colE, Bs + (s - 4) * 512);
      }
      __syncthreads();
      bf16x8 af[2], bfr[2];
#pragma unroll
      for (int i = 0; i < 2; i++)
        af[i] = *(const bf16x8*)&As[(wr + i * 16 + r16) * 32 + kg];
#pragma unroll
      for (int j = 0; j < 2; j++)
        bfr[j] = *(const bf16x8*)&Bs[(wc + j * 16 + r16) * 32 + kg];
#pragma unroll
      for (int i = 0; i < 2; i++)
#pragma unroll
        for (int j = 0; j < 2; j++)
          acc[i][j] = __builtin_amdgcn_mfma_f32_16x16x32_bf16(af[i], bfr[j], acc[i][j], 0, 0, 0);
    }
    const int col16 = lane & 15;
    const int rowg = (lane >> 4) * 4;
#pragma unroll
    for (int i = 0; i < 2; i++) {
      int row = m0 + wr + i * 16 + rowg;
#pragma unroll
      for (int j = 0; j < 2; j++) {
        int col = n0 + wc + j * 16 + col16;
        float bv = bias[col];
#pragma unroll
        for (int q = 0; q < 4; q++)
          aout[(size_t)(row + q) * 512 + col] = f2bf(acc[i][j][q] + bv);
      }
    }
  } else {
    const int kb = (blockIdx.x - 8) * 64 + blockIdx.y;
    const int row = kb * 4 + wid;
    const int b = row >> 9, q = row & 511;
    const float prior = 1.0f / 512.0f + 1e-8f;
    float hs[8] = {0.f, 0.f, 0.f, 0.f, 0.f, 0.f, 0.f, 0.f};
#pragma unroll
    for (int h = 0; h < 8; ++h) {
      bf16x8 v = *(const bf16x8*)&P[(((size_t)(b * 8 + h)) * 512 + q) * 512 + lane * 8];
#pragma unroll
      for (int k = 0; k < 8; ++k) hs[k] += bf2f((unsigned short)v[k]);
    }
    float s = 0.f;
#pragma unroll
    for (int k = 0; k < 8; ++k) {
      float a = hs[k] * 0.125f + 1e-8f;
      s += a * __logf(a / prior);
    }
#pragma unroll
    for (int m = 32; m; m >>= 1) s += __shfl_xor(s, m, 64);
    if (lane == 0) assoc[row] = FIRST ? s : (assoc[row] + s);
  }
}

// ---------------- layernorm in-place on bf16 residual stream ----------------
__global__ __launch_bounds__(256) void ln_kernel(const short* __restrict__ res,
                                                 const float* __restrict__ g,
                                                 const float* __restrict__ bta,
                                                 short* __restrict__ hbf) {
  const int wid = threadIdx.x >> 6, lane = threadIdx.x & 63;
  const size_t row = (size_t)blockIdx.x * 4 + wid;
  bf16x8 hv = *(const bf16x8*)&hbf[row * 512 + lane * 8];
  bf16x8 rv = *(const bf16x8*)&res[row * 512 + lane * 8];
  float v[8], s = 0.f, s2 = 0.f;
#pragma unroll
  for (int i = 0; i < 8; i++) {
    v[i] = bf2f((unsigned short)hv[i]) + bf2f((unsigned short)rv[i]);
    s += v[i];
    s2 += v[i] * v[i];
  }
#pragma unroll
  for (int m = 32; m; m >>= 1) {
    s += __shfl_xor(s, m, 64);
    s2 += __shfl_xor(s2, m, 64);
  }
  float mu = s * (1.0f / 512.0f);
  float var = s2 * (1.0f / 512.0f) - mu * mu;
  float rs = rsqrtf(var + 1e-5f);
  const float* gp = g + lane * 8;
  const float* bp = bta + lane * 8;
  bf16x8 ob;
#pragma unroll
  for (int i = 0; i < 8; i++) ob[i] = f2bf((v[i] - mu) * rs * gp[i] + bp[i]);
  *(bf16x8*)&hbf[row * 512 + lane * 8] = ob;
}

// ---------------- reconstruction via MFMA: out[4096,32] = h_bf @ WoutT^T + bout ----------------
__global__ __launch_bounds__(256) void recon_mfma(const short* __restrict__ hbf,
                                                  const short* __restrict__ WoutT,
                                                  const float* __restrict__ bout,
                                                  float* __restrict__ out) {
  const int wid = threadIdx.x >> 6, lane = threadIdx.x & 63;
  const int r16 = lane & 15, kg = (lane >> 4) * 8;
  const int wbase = blockIdx.x * 128 + wid * 32;

  f32x4 acc[2][2];
#pragma unroll
  for (int i = 0; i < 2; i++)
#pragma unroll
    for (int j = 0; j < 2; j++)
#pragma unroll
      for (int q = 0; q < 4; q++) acc[i][j][q] = 0.0f;

  for (int kt = 0; kt < 512; kt += 32) {
    bf16x8 af[2], bfr[2];
#pragma unroll
    for (int i = 0; i < 2; i++)
      af[i] = *(const bf16x8*)&hbf[(size_t)(wbase + i * 16 + r16) * 512 + kt + kg];
#pragma unroll
    for (int j = 0; j < 2; j++)
      bfr[j] = *(const bf16x8*)&WoutT[(size_t)(j * 16 + r16) * 512 + kt + kg];
#pragma unroll
    for (int i = 0; i < 2; i++)
#pragma unroll
      for (int j = 0; j < 2; j++)
        acc[i][j] = __builtin_amdgcn_mfma_f32_16x16x32_bf16(af[i], bfr[j], acc[i][j], 0, 0, 0);
  }

  const int rowg = (lane >> 4) * 4;
#pragma unroll
  for (int i = 0; i < 2; i++)
#pragma unroll
    for (int j = 0; j < 2; j++) {
      int col = j * 16 + r16;
#pragma unroll
      for (int q = 0; q < 4; q++)
        out[(size_t)(wbase + i * 16 + rowg + q) * 32 + col] = acc[i][j][q] + bout[col];
    }
}

// ---------------- score stage 2 + assoc output ----------------
__global__ __launch_bounds__(256) void score2_kernel(const short* __restrict__ s1,
                                                     const float* __restrict__ Ws2,
                                                     const float* __restrict__ bs2,
                                                     const float* __restrict__ assoc,
                                                     float* __restrict__ outScore,
                                                     float* __restrict__ outAssoc) {
  const int wid = threadIdx.x >> 6, lane = threadIdx.x & 63;
  const int row = blockIdx.x * 4 + wid;
  const short* rp = &s1[(size_t)row * 256 + lane * 4];
  float d = 0.f;
#pragma unroll
  for (int e = 0; e < 4; e++) d += bf2f((unsigned short)rp[e]) * Ws2[lane * 4 + e];
#pragma unroll
  for (int m = 32; m; m >>= 1) d += __shfl_xor(d, m, 64);
  if (lane == 0) {
    outScore[row] = 1.f / (1.f + __expf(-(d + bs2[0])));
    outAssoc[row] = assoc[row] * (1.0f / 6.0f);
  }
}

extern "C" void kernel_launch(void* const* d_in, const int* in_sizes, int n_in,
                              void* d_out, int out_size, void* d_ws, size_t ws_size,
                              hipStream_t stream) {
  const float* x    = (const float*)d_in[0];
  const float* W_in = (const float*)d_in[1];
  const float* b_in = (const float*)d_in[2];
  const float* pe   = (const float*)d_in[3];
  const float* Wq   = (const float*)d_in[4];
  const float* Wk   = (const float*)d_in[5];
  const float* Wv   = (const float*)d_in[6];
  const float* Wo   = (const float*)d_in[7];
  const float* bo   = (const float*)d_in[8];
  const float* W1   = (const float*)d_in[9];
  const float* b1   = (const float*)d_in[10];
  const float* W2   = (const float*)d_in[11];
  const float* b2   = (const float*)d_in[12];
  const float* ln1g = (const float*)d_in[13];
  const float* ln1b = (const float*)d_in[14];
  const float* ln2g = (const float*)d_in[15];
  const float* ln2b = (const float*)d_in[16];
  const float* Wout = (const float*)d_in[17];
  const float* bout = (const float*)d_in[18];
  const float* Ws1  = (const float*)d_in[19];
  const float* bs1  = (const float*)d_in[20];
  const float* Ws2  = (const float*)d_in[21];
  const float* bs2  = (const float*)d_in[22];

  char* p = (char*)d_ws;
  auto alloc = [&](size_t bytes) {
    void* r = (void*)p;
    p += (bytes + 255) & ~(size_t)255;
    return r;
  };
  short* h_bf  = (short*)alloc((size_t)4096 * 512 * 2);
  short* qh    = (short*)alloc((size_t)4096 * 1536 * 2);
  short* aout  = (short*)alloc((size_t)4096 * 512 * 2);
  short* ctxb  = (short*)alloc((size_t)4096 * 512 * 2);
  short* ff1b  = (short*)alloc((size_t)4096 * 2048 * 2);
  short* ff2   = (short*)alloc((size_t)4096 * 512 * 2);
  float* assoc = (float*)alloc((size_t)4096 * 4);
  short* Pbuf  = (short*)alloc((size_t)64 * 512 * 512 * 2);
  short* Vt    = (short*)alloc((size_t)64 * 64 * 512 * 2);
  short* sc1   = (short*)alloc((size_t)4096 * 256 * 2);
  short* qkvt  = (short*)alloc((size_t)6 * 1536 * 512 * 2);
  short* wot   = (short*)alloc((size_t)6 * 512 * 512 * 2);
  short* w1t   = (short*)alloc((size_t)6 * 2048 * 512 * 2);
  short* w2t   = (short*)alloc((size_t)6 * 512 * 2048 * 2);
  short* ws1t  = (short*)alloc((size_t)256 * 512 * 2);
  short* woutT = (short*)alloc((size_t)32 * 512 * 2);

  prologue_kernel<<<26768, 256, 0, stream>>>(x, W_in, b_in, pe, h_bf, Wq, Wk, Wv, Wo, W1, W2,
                                             Ws1, Wout, qkvt, wot, w1t, w2t, ws1t, woutT);

  for (int l = 0; l < 6; ++l) {
    gemm_bt<5, 128, 128, 32><<<dim3(12, 32), 256, 0, stream>>>(
        h_bf, qkvt + (size_t)l * 786432, qh, nullptr, 4096, 1536, 512);
    vt_kernel<<<dim3(16, 2, 64), 256, 0, stream>>>(qh, Vt);
    smpv_kernel<<<dim3(32, 64), 256, 0, stream>>>(qh, Vt, Pbuf, ctxb);
    if (l == 0)
      wo_kl_kernel<1><<<dim3(24, 64), 256, 0, stream>>>(ctxb, wot + (size_t)l * 262144,
                                                        bo + l * 512, aout, Pbuf, assoc);
    else
      wo_kl_kernel<0><<<dim3(24, 64), 256, 0, stream>>>(ctxb, wot + (size_t)l * 262144,
                                                        bo + l * 512, aout, Pbuf, assoc);
    ln_kernel<<<1024, 256, 0, stream>>>(aout, ln1g + l * 512, ln1b + l * 512, h_bf);
    gemm_bt<2, 128, 128, 32><<<dim3(16, 32), 256, 0, stream>>>(
        h_bf, w1t + (size_t)l * 1048576, ff1b, b1 + l * 2048, 4096, 2048, 512);
    gemm_bt<4, 64, 64, 32><<<dim3(8, 64), 256, 0, stream>>>(
        ff1b, w2t + (size_t)l * 1048576, ff2, b2 + l * 512, 4096, 512, 2048);
    ln_kernel<<<1024, 256, 0, stream>>>(ff2, ln2g + l * 512, ln2b + l * 512, h_bf);
  }

  float* out = (float*)d_out;
  recon_mfma<<<32, 256, 0, stream>>>(h_bf, woutT, bout, out);
  gemm_bt<2, 128, 128, 32><<<dim3(2, 32), 256, 0, stream>>>(h_bf, ws1t, sc1, bs1,
                                                            4096, 256, 512);
  score2_kernel<<<1024, 256, 0, stream>>>(sc1, Ws2, bs2, assoc, out + 131072,
                                          out + 131072 + 4096);
}

// Round 14
// 746.880 us; speedup vs baseline: 1.1168x; 1.0673x over previous
//
#include <hip/hip_runtime.h>
#include <math.h>

typedef __attribute__((ext_vector_type(8))) short bf16x8;
typedef __attribute__((ext_vector_type(4))) float f32x4;

__device__ __forceinline__ short f2bf(float v) {
  union { float f; unsigned u; } x; x.f = v;
  unsigned r = x.u + 0x7fffu + ((x.u >> 16) & 1u);
  return (short)(r >> 16);
}

__device__ __forceinline__ float bf2f(unsigned short u) {
  union { unsigned u; float f; } x; x.u = ((unsigned)u) << 16;
  return x.f;
}

__device__ __forceinline__ void gld_lds16(const void* g, void* l) {
  __builtin_amdgcn_global_load_lds((const __attribute__((address_space(1))) void*)g,
                                   (__attribute__((address_space(3))) void*)l, 16, 0, 0);
}

// ---------------- mega prologue: embed + ALL weight transposes in one dispatch ----------------
__global__ __launch_bounds__(256) void prologue_kernel(
    const float* __restrict__ x, const float* __restrict__ W_in, const float* __restrict__ b_in,
    const float* __restrict__ pe, short* __restrict__ hbf,
    const float* __restrict__ Wq, const float* __restrict__ Wk, const float* __restrict__ Wv,
    const float* __restrict__ Wo, const float* __restrict__ W1, const float* __restrict__ W2,
    const float* __restrict__ Ws1, const float* __restrict__ Wout,
    short* __restrict__ qkvt, short* __restrict__ wot, short* __restrict__ w1t,
    short* __restrict__ w2t, short* __restrict__ ws1t, short* __restrict__ woutT) {
  __shared__ float t[32][33];
  const int tid = threadIdx.x;
  int idx = blockIdx.x;
  if (idx < 8192) {  // ---- embed: h_bf = bf16(x @ W_in + b_in + pe) ----
    int col = (idx & 1) * 256 + tid;
    int row = idx >> 1;
    int s = row & 511;
    float a = b_in[col] + pe[s * 512 + col];
    const float* xr = x + (size_t)row * 32;
#pragma unroll
    for (int k = 0; k < 32; k++) a += xr[k] * W_in[k * 512 + col];
    hbf[(size_t)row * 512 + col] = f2bf(a);
    return;
  }
  idx -= 8192;
  const float* src;
  short* dst;
  int R, C, cx, cy;
  if (idx < 4608) {  // qkv: 18 z x (16x16)
    int z = idx >> 8, rem = idx & 255;
    cx = rem & 15; cy = rem >> 4;
    int which = z / 6, l = z % 6;
    src = (which == 0 ? Wq : which == 1 ? Wk : Wv) + (size_t)l * 262144;
    dst = qkvt + (size_t)l * 786432 + (size_t)which * 262144;
    R = 512; C = 512;
  } else if (idx < 6144) {  // wo: 6 z x (16x16)
    int j = idx - 4608;
    int l = j >> 8, rem = j & 255;
    cx = rem & 15; cy = rem >> 4;
    src = Wo + (size_t)l * 262144; dst = wot + (size_t)l * 262144;
    R = 512; C = 512;
  } else if (idx < 12288) {  // w1: 6 z x (64x16)
    int j = idx - 6144;
    int l = j >> 10, rem = j & 1023;
    cx = rem & 63; cy = rem >> 6;
    src = W1 + (size_t)l * 1048576; dst = w1t + (size_t)l * 1048576;
    R = 512; C = 2048;
  } else if (idx < 18432) {  // w2: 6 z x (16x64)
    int j = idx - 12288;
    int l = j >> 10, rem = j & 1023;
    cx = rem & 15; cy = rem >> 4;
    src = W2 + (size_t)l * 1048576; dst = w2t + (size_t)l * 1048576;
    R = 2048; C = 512;
  } else if (idx < 18560) {  // ws1: (8x16)
    int j = idx - 18432;
    cx = j & 7; cy = j >> 3;
    src = Ws1; dst = ws1t; R = 512; C = 256;
  } else {  // wout: (1x16)
    int j = idx - 18560;
    cx = 0; cy = j;
    src = Wout; dst = woutT; R = 512; C = 32;
  }
  const int tx = tid & 31, ty = tid >> 5;
  const int c0 = cx * 32, r0 = cy * 32;
#pragma unroll
  for (int i = 0; i < 4; i++)
    t[ty + i * 8][tx] = src[(size_t)(r0 + ty + i * 8) * C + c0 + tx];
  __syncthreads();
#pragma unroll
  for (int i = 0; i < 4; i++)
    dst[(size_t)(c0 + ty + i * 8) * R + r0 + tx] = f2bf(t[tx][ty + i * 8]);
}

// ---------------- bf16 GEMM: A[M,K] x Bt[N,K]^T -> C[M,N] ----------------
// EPI: 2 bf16+bias+relu; 4 bf16+bias; 5 bf16 QKV->dense per-head layout (coalesced)
// BK=64 with BOTH-SIDES swizzle (rule #21): global_load_lds dest stays linear; the
// per-lane GLOBAL source chunk is pre-swizzled (chunk = lane%CPR ^ rowL&(CPR-1)), and
// fragment reads XOR the same mask -> wave b128 reads hit all 32 banks evenly (8/bank
// floor). r4's unswizzled BK=64 was 16-way-conflicted (4.7M/dispatch); this is the fix.
// Accumulation order identical to BK=32 (kk inner, sequential k) -> bit-identical.
template <int EPI, int BM, int BN, int BK>
__global__ __launch_bounds__(256) void gemm_bt(const short* __restrict__ A,
                                               const short* __restrict__ Bt,
                                               short* __restrict__ Cb,
                                               const float* __restrict__ bias,
                                               int M, int N, int K) {
  __shared__ short As[BM * BK];
  __shared__ short Bs[BN * BK];
  const int tid = threadIdx.x;
  const int wid = tid >> 6;
  const int lane = tid & 63;
  const int m0 = blockIdx.y * BM;
  const int n0 = blockIdx.x * BN;
  constexpr int WR = BM / 2, WC = BN / 2, FI = WR / 16, FJ = WC / 16, KK = BK / 32;
  constexpr int CPR = BK / 8;   // 16B chunks per LDS row
  constexpr int SM = CPR - 1;   // swizzle mask
  const int wr = (wid >> 1) * WR;
  const int wc = (wid & 1) * WC;

  f32x4 acc[FI][FJ];
#pragma unroll
  for (int i = 0; i < FI; i++)
#pragma unroll
    for (int j = 0; j < FJ; j++)
#pragma unroll
      for (int q = 0; q < 4; q++) acc[i][j][q] = 0.0f;

  const short* aBase = A + (size_t)m0 * K;
  const short* bBase = Bt + (size_t)n0 * K;
  constexpr int RPC = 512 / BK;        // rows staged per gld_lds call (1024B)
  constexpr int CA = BM / RPC;
  constexpr int CT = (BM + BN) / RPC;
  const int rowL = lane / CPR;                              // lane's row within call
  const int colE = ((lane % CPR) ^ (rowL & SM)) * 8;        // pre-swizzled global chunk
  const int g = lane >> 4;
  const int r16 = lane & 15;
  const int rsw = r16 & SM;

  for (int kt = 0; kt < K; kt += BK) {
    __syncthreads();
#pragma unroll
    for (int c = 0; c < CT / 4; ++c) {
      int s = c * 4 + wid;
      if (s < CA)
        gld_lds16(aBase + (size_t)(s * RPC + rowL) * K + kt + colE, As + s * 512);
      else
        gld_lds16(bBase + (size_t)((s - CA) * RPC + rowL) * K + kt + colE, Bs + (s - CA) * 512);
    }
    __syncthreads();
    bf16x8 af[FI][KK], bfr[FJ][KK];
#pragma unroll
    for (int i = 0; i < FI; i++)
#pragma unroll
      for (int kk = 0; kk < KK; kk++)
        af[i][kk] = *(const bf16x8*)&As[(wr + i * 16 + r16) * BK + (((kk * 4 + g) ^ rsw) * 8)];
#pragma unroll
    for (int j = 0; j < FJ; j++)
#pragma unroll
      for (int kk = 0; kk < KK; kk++)
        bfr[j][kk] = *(const bf16x8*)&Bs[(wc + j * 16 + r16) * BK + (((kk * 4 + g) ^ rsw) * 8)];
#pragma unroll
    for (int kk = 0; kk < KK; kk++)
#pragma unroll
      for (int i = 0; i < FI; i++)
#pragma unroll
        for (int j = 0; j < FJ; j++)
          acc[i][j] = __builtin_amdgcn_mfma_f32_16x16x32_bf16(af[i][kk], bfr[j][kk], acc[i][j], 0, 0, 0);
  }

  const int col16 = lane & 15;
  const int rowg = (lane >> 4) * 4;
#pragma unroll
  for (int i = 0; i < FI; i++) {
    int row = m0 + wr + i * 16 + rowg;
#pragma unroll
    for (int j = 0; j < FJ; j++) {
      int col = n0 + wc + j * 16 + col16;
      float bv = (EPI == 2 || EPI == 4) ? bias[col] : 0.0f;
#pragma unroll
      for (int q = 0; q < 4; q++) {
        float v = acc[i][j][q] + bv;
        if (EPI == 2) {
          v = fmaxf(v, 0.0f);
          Cb[(size_t)(row + q) * N + col] = f2bf(v);
        } else if (EPI == 5) {
          int rr = row + q;
          int sect = col >> 9, hh = (col >> 6) & 7, dk = col & 63;
          int bq = rr >> 9, tt = rr & 511;
          Cb[(((size_t)(sect * 64 + bq * 8 + hh)) * 512 + tt) * 64 + dk] = f2bf(v);
        } else {
          Cb[(size_t)(row + q) * N + col] = f2bf(v);
        }
      }
    }
  }
}

// ---------------- V transpose (dense layout): qh V-section -> Vt[bh][64 dk][512 t] ----------------
__global__ __launch_bounds__(256) void vt_kernel(const short* __restrict__ qh,
                                                 short* __restrict__ Vt) {
  __shared__ short t[32][34];
  const int bh = blockIdx.z;
  const int t0 = blockIdx.x * 32, d0 = blockIdx.y * 32;
  const int tx = threadIdx.x & 31, ty = threadIdx.x >> 5;
  const short* Vh = qh + (size_t)(128 + bh) * 512 * 64;
#pragma unroll
  for (int i = 0; i < 4; i++)
    t[ty + i * 8][tx] = Vh[(size_t)(t0 + ty + i * 8) * 64 + d0 + tx];
  __syncthreads();
#pragma unroll
  for (int i = 0; i < 4; i++)
    Vt[((size_t)bh * 64 + d0 + ty + i * 8) * 512 + t0 + tx] = t[tx][ty + i * 8];
}

// ---------------- fused scores+softmax+P dump+PV: per (bh, 16-query tile) ----------------
// ~40us floor across 3 structures (r9-r11): per-wave serial work, not occupancy.
__global__ __launch_bounds__(256) void smpv_kernel(const short* __restrict__ qh,
                                                   const short* __restrict__ Vt,
                                                   short* __restrict__ P,
                                                   short* __restrict__ ctxb) {
  __shared__ short Pl[16 * 512];  // 16KB, [q][t] bf16, swizzled byte^=(q&7)<<4
  __shared__ float red0[4][16];
  __shared__ float red1[4][16];
  const int bh = blockIdx.y, b = bh >> 3, h = bh & 7;
  const int q0 = blockIdx.x * 16;
  const int tid = threadIdx.x;
  const int wid = tid >> 6, lane = tid & 63;
  const int r16 = lane & 15, g = lane >> 4;

  const short* Qh = qh + ((size_t)bh * 512) * 64;
  const short* Kh = qh + ((size_t)(64 + bh) * 512) * 64;

  const short* qp = Qh + (size_t)(q0 + r16) * 64 + g * 8;
  const bf16x8 qa0 = *(const bf16x8*)qp;
  const bf16x8 qa1 = *(const bf16x8*)(qp + 32);

  f32x4 acc[8];
#pragma unroll
  for (int tt = 0; tt < 8; ++tt) {
    const short* kp = Kh + (size_t)(wid * 128 + tt * 16 + r16) * 64 + g * 8;
    bf16x8 kb0 = *(const bf16x8*)kp;
    bf16x8 kb1 = *(const bf16x8*)(kp + 32);
    f32x4 c = {0.f, 0.f, 0.f, 0.f};
    c = __builtin_amdgcn_mfma_f32_16x16x32_bf16(qa0, kb0, c, 0, 0, 0);
    c = __builtin_amdgcn_mfma_f32_16x16x32_bf16(qa1, kb1, c, 0, 0, 0);
    acc[tt] = c;
  }

  float mx[4] = {-1e30f, -1e30f, -1e30f, -1e30f};
#pragma unroll
  for (int tt = 0; tt < 8; ++tt)
#pragma unroll
    for (int r = 0; r < 4; ++r) mx[r] = fmaxf(mx[r], acc[tt][r]);
#pragma unroll
  for (int r = 0; r < 4; ++r)
#pragma unroll
    for (int m = 8; m; m >>= 1) mx[r] = fmaxf(mx[r], __shfl_xor(mx[r], m, 16));
  if (r16 == 0) {
#pragma unroll
    for (int r = 0; r < 4; ++r) red0[wid][g * 4 + r] = mx[r];
  }
  __syncthreads();
#pragma unroll
  for (int r = 0; r < 4; ++r) {
    int q = g * 4 + r;
    mx[r] = fmaxf(fmaxf(red0[0][q], red0[1][q]), fmaxf(red0[2][q], red0[3][q]));
  }
  float sum[4] = {0.f, 0.f, 0.f, 0.f};
#pragma unroll
  for (int tt = 0; tt < 8; ++tt)
#pragma unroll
    for (int r = 0; r < 4; ++r) {
      float e = __expf((acc[tt][r] - mx[r]) * 0.125f);
      acc[tt][r] = e;
      sum[r] += e;
    }
#pragma unroll
  for (int r = 0; r < 4; ++r)
#pragma unroll
    for (int m = 8; m; m >>= 1) sum[r] += __shfl_xor(sum[r], m, 16);
  if (r16 == 0) {
#pragma unroll
    for (int r = 0; r < 4; ++r) red1[wid][g * 4 + r] = sum[r];
  }
  __syncthreads();

  char* plc = (char*)Pl;
#pragma unroll
  for (int r = 0; r < 4; ++r) {
    int q = g * 4 + r;
    float inv = 1.0f / (red1[0][q] + red1[1][q] + red1[2][q] + red1[3][q]);
    int swz = (q & 7) << 4;
#pragma unroll
    for (int tt = 0; tt < 8; ++tt)
      *(short*)(plc + q * 1024 + (((wid * 128 + tt * 16 + r16) * 2) ^ swz)) =
          f2bf(acc[tt][r] * inv);
  }
  __syncthreads();

  short* pg = P + ((size_t)bh * 512 + q0) * 512;
#pragma unroll
  for (int k = 0; k < 4; ++k) {
    int c = k * 256 + tid;
    int q = c >> 6;
    int tB = (c & 63) * 16;
    bf16x8 v = *(const bf16x8*)(plc + q * 1024 + (tB ^ ((q & 7) << 4)));
    *(bf16x8*)&pg[(size_t)q * 512 + (c & 63) * 8] = v;
  }

  // PV: dual accumulators break the 16-deep dependent MFMA chain into 2x8
  f32x4 pacc0 = {0.f, 0.f, 0.f, 0.f}, pacc1 = {0.f, 0.f, 0.f, 0.f};
  const short* vb = Vt + (size_t)bh * 64 * 512 + (size_t)(wid * 16) * 512;
  const int rswz = (r16 & 7) << 4;
  for (int kt = 0; kt < 512; kt += 64) {
    bf16x8 af0 = *(const bf16x8*)(plc + r16 * 1024 + (((kt + g * 8) * 2) ^ rswz));
    bf16x8 af1 = *(const bf16x8*)(plc + r16 * 1024 + (((kt + 32 + g * 8) * 2) ^ rswz));
    bf16x8 b0 = *(const bf16x8*)&vb[(size_t)r16 * 512 + kt + g * 8];
    bf16x8 b1 = *(const bf16x8*)&vb[(size_t)r16 * 512 + kt + 32 + g * 8];
    pacc0 = __builtin_amdgcn_mfma_f32_16x16x32_bf16(af0, b0, pacc0, 0, 0, 0);
    pacc1 = __builtin_amdgcn_mfma_f32_16x16x32_bf16(af1, b1, pacc1, 0, 0, 0);
  }
  const int col = h * 64 + wid * 16 + r16;
#pragma unroll
  for (int q = 0; q < 4; ++q)
    ctxb[(size_t)(b * 512 + q0 + g * 4 + q) * 512 + col] = f2bf(pacc0[q] + pacc1[q]);
}

// ---------------- grid-union: Wo 64x64 GEMM (x<8) + KL head-sum (x>=8) ----------------
template <int FIRST>
__global__ __launch_bounds__(256) void wo_kl_kernel(const short* __restrict__ A,
                                                    const short* __restrict__ Bt,
                                                    const float* __restrict__ bias,
                                                    short* __restrict__ aout,
                                                    const short* __restrict__ P,
                                                    float* __restrict__ assoc) {
  __shared__ short As[64 * 32];
  __shared__ short Bs[64 * 32];
  const int tid = threadIdx.x;
  const int wid = tid >> 6, lane = tid & 63;
  if (blockIdx.x < 8) {
    const int m0 = blockIdx.y * 64;
    const int n0 = blockIdx.x * 64;
    const int wr = (wid >> 1) * 32;
    const int wc = (wid & 1) * 32;
    f32x4 acc[2][2];
#pragma unroll
    for (int i = 0; i < 2; i++)
#pragma unroll
      for (int j = 0; j < 2; j++)
#pragma unroll
        for (int q = 0; q < 4; q++) acc[i][j][q] = 0.0f;
    const short* aBase = A + (size_t)m0 * 512;
    const short* bBase = Bt + (size_t)n0 * 512;
    const int rowL = lane >> 2;
    const int colE = (lane & 3) * 8;
    const int kg = (lane >> 4) * 8;
    const int r16 = lane & 15;
    for (int kt = 0; kt < 512; kt += 32) {
      __syncthreads();
#pragma unroll
      for (int c = 0; c < 2; ++c) {
        int s = c * 4 + wid;
        if (s < 4)
          gld_lds16(aBase + (size_t)(s * 16 + rowL) * 512 + kt + colE, As + s * 512);
        else
          gld_lds16(bBase + (size_t)((s - 4) * 16 + rowL) * 512 + kt + colE, Bs + (s - 4) * 512);
      }
      __syncthreads();
      bf16x8 af[2], bfr[2];
#pragma unroll
      for (int i = 0; i < 2; i++)
        af[i] = *(const bf16x8*)&As[(wr + i * 16 + r16) * 32 + kg];
#pragma unroll
      for (int j = 0; j < 2; j++)
        bfr[j] = *(const bf16x8*)&Bs[(wc + j * 16 + r16) * 32 + kg];
#pragma unroll
      for (int i = 0; i < 2; i++)
#pragma unroll
        for (int j = 0; j < 2; j++)
          acc[i][j] = __builtin_amdgcn_mfma_f32_16x16x32_bf16(af[i], bfr[j], acc[i][j], 0, 0, 0);
    }
    const int col16 = lane & 15;
    const int rowg = (lane >> 4) * 4;
#pragma unroll
    for (int i = 0; i < 2; i++) {
      int row = m0 + wr + i * 16 + rowg;
#pragma unroll
      for (int j = 0; j < 2; j++) {
        int col = n0 + wc + j * 16 + col16;
        float bv = bias[col];
#pragma unroll
        for (int q = 0; q < 4; q++)
          aout[(size_t)(row + q) * 512 + col] = f2bf(acc[i][j][q] + bv);
      }
    }
  } else {
    const int kb = (blockIdx.x - 8) * 64 + blockIdx.y;
    const int row = kb * 4 + wid;
    const int b = row >> 9, q = row & 511;
    const float prior = 1.0f / 512.0f + 1e-8f;
    float hs[8] = {0.f, 0.f, 0.f, 0.f, 0.f, 0.f, 0.f, 0.f};
#pragma unroll
    for (int h = 0; h < 8; ++h) {
      bf16x8 v = *(const bf16x8*)&P[(((size_t)(b * 8 + h)) * 512 + q) * 512 + lane * 8];
#pragma unroll
      for (int k = 0; k < 8; ++k) hs[k] += bf2f((unsigned short)v[k]);
    }
    float s = 0.f;
#pragma unroll
    for (int k = 0; k < 8; ++k) {
      float a = hs[k] * 0.125f + 1e-8f;
      s += a * __logf(a / prior);
    }
#pragma unroll
    for (int m = 32; m; m >>= 1) s += __shfl_xor(s, m, 64);
    if (lane == 0) assoc[row] = FIRST ? s : (assoc[row] + s);
  }
}

// ---------------- layernorm in-place on bf16 residual stream ----------------
__global__ __launch_bounds__(256) void ln_kernel(const short* __restrict__ res,
                                                 const float* __restrict__ g,
                                                 const float* __restrict__ bta,
                                                 short* __restrict__ hbf) {
  const int wid = threadIdx.x >> 6, lane = threadIdx.x & 63;
  const size_t row = (size_t)blockIdx.x * 4 + wid;
  bf16x8 hv = *(const bf16x8*)&hbf[row * 512 + lane * 8];
  bf16x8 rv = *(const bf16x8*)&res[row * 512 + lane * 8];
  float v[8], s = 0.f, s2 = 0.f;
#pragma unroll
  for (int i = 0; i < 8; i++) {
    v[i] = bf2f((unsigned short)hv[i]) + bf2f((unsigned short)rv[i]);
    s += v[i];
    s2 += v[i] * v[i];
  }
#pragma unroll
  for (int m = 32; m; m >>= 1) {
    s += __shfl_xor(s, m, 64);
    s2 += __shfl_xor(s2, m, 64);
  }
  float mu = s * (1.0f / 512.0f);
  float var = s2 * (1.0f / 512.0f) - mu * mu;
  float rs = rsqrtf(var + 1e-5f);
  const float* gp = g + lane * 8;
  const float* bp = bta + lane * 8;
  bf16x8 ob;
#pragma unroll
  for (int i = 0; i < 8; i++) ob[i] = f2bf((v[i] - mu) * rs * gp[i] + bp[i]);
  *(bf16x8*)&hbf[row * 512 + lane * 8] = ob;
}

// ---------------- reconstruction via MFMA: out[4096,32] = h_bf @ WoutT^T + bout ----------------
__global__ __launch_bounds__(256) void recon_mfma(const short* __restrict__ hbf,
                                                  const short* __restrict__ WoutT,
                                                  const float* __restrict__ bout,
                                                  float* __restrict__ out) {
  const int wid = threadIdx.x >> 6, lane = threadIdx.x & 63;
  const int r16 = lane & 15, kg = (lane >> 4) * 8;
  const int wbase = blockIdx.x * 128 + wid * 32;

  f32x4 acc[2][2];
#pragma unroll
  for (int i = 0; i < 2; i++)
#pragma unroll
    for (int j = 0; j < 2; j++)
#pragma unroll
      for (int q = 0; q < 4; q++) acc[i][j][q] = 0.0f;

  for (int kt = 0; kt < 512; kt += 32) {
    bf16x8 af[2], bfr[2];
#pragma unroll
    for (int i = 0; i < 2; i++)
      af[i] = *(const bf16x8*)&hbf[(size_t)(wbase + i * 16 + r16) * 512 + kt + kg];
#pragma unroll
    for (int j = 0; j < 2; j++)
      bfr[j] = *(const bf16x8*)&WoutT[(size_t)(j * 16 + r16) * 512 + kt + kg];
#pragma unroll
    for (int i = 0; i < 2; i++)
#pragma unroll
      for (int j = 0; j < 2; j++)
        acc[i][j] = __builtin_amdgcn_mfma_f32_16x16x32_bf16(af[i], bfr[j], acc[i][j], 0, 0, 0);
  }

  const int rowg = (lane >> 4) * 4;
#pragma unroll
  for (int i = 0; i < 2; i++)
#pragma unroll
    for (int j = 0; j < 2; j++) {
      int col = j * 16 + r16;
#pragma unroll
      for (int q = 0; q < 4; q++)
        out[(size_t)(wbase + i * 16 + rowg + q) * 32 + col] = acc[i][j][q] + bout[col];
    }
}

// ---------------- score stage 2 + assoc output ----------------
__global__ __launch_bounds__(256) void score2_kernel(const short* __restrict__ s1,
                                                     const float* __restrict__ Ws2,
                                                     const float* __restrict__ bs2,
                                                     const float* __restrict__ assoc,
                                                     float* __restrict__ outScore,
                                                     float* __restrict__ outAssoc) {
  const int wid = threadIdx.x >> 6, lane = threadIdx.x & 63;
  const int row = blockIdx.x * 4 + wid;
  const short* rp = &s1[(size_t)row * 256 + lane * 4];
  float d = 0.f;
#pragma unroll
  for (int e = 0; e < 4; e++) d += bf2f((unsigned short)rp[e]) * Ws2[lane * 4 + e];
#pragma unroll
  for (int m = 32; m; m >>= 1) d += __shfl_xor(d, m, 64);
  if (lane == 0) {
    outScore[row] = 1.f / (1.f + __expf(-(d + bs2[0])));
    outAssoc[row] = assoc[row] * (1.0f / 6.0f);
  }
}

extern "C" void kernel_launch(void* const* d_in, const int* in_sizes, int n_in,
                              void* d_out, int out_size, void* d_ws, size_t ws_size,
                              hipStream_t stream) {
  const float* x    = (const float*)d_in[0];
  const float* W_in = (const float*)d_in[1];
  const float* b_in = (const float*)d_in[2];
  const float* pe   = (const float*)d_in[3];
  const float* Wq   = (const float*)d_in[4];
  const float* Wk   = (const float*)d_in[5];
  const float* Wv   = (const float*)d_in[6];
  const float* Wo   = (const float*)d_in[7];
  const float* bo   = (const float*)d_in[8];
  const float* W1   = (const float*)d_in[9];
  const float* b1   = (const float*)d_in[10];
  const float* W2   = (const float*)d_in[11];
  const float* b2   = (const float*)d_in[12];
  const float* ln1g = (const float*)d_in[13];
  const float* ln1b = (const float*)d_in[14];
  const float* ln2g = (const float*)d_in[15];
  const float* ln2b = (const float*)d_in[16];
  const float* Wout = (const float*)d_in[17];
  const float* bout = (const float*)d_in[18];
  const float* Ws1  = (const float*)d_in[19];
  const float* bs1  = (const float*)d_in[20];
  const float* Ws2  = (const float*)d_in[21];
  const float* bs2  = (const float*)d_in[22];

  char* p = (char*)d_ws;
  auto alloc = [&](size_t bytes) {
    void* r = (void*)p;
    p += (bytes + 255) & ~(size_t)255;
    return r;
  };
  short* h_bf  = (short*)alloc((size_t)4096 * 512 * 2);
  short* qh    = (short*)alloc((size_t)4096 * 1536 * 2);
  short* aout  = (short*)alloc((size_t)4096 * 512 * 2);
  short* ctxb  = (short*)alloc((size_t)4096 * 512 * 2);
  short* ff1b  = (short*)alloc((size_t)4096 * 2048 * 2);
  short* ff2   = (short*)alloc((size_t)4096 * 512 * 2);
  float* assoc = (float*)alloc((size_t)4096 * 4);
  short* Pbuf  = (short*)alloc((size_t)64 * 512 * 512 * 2);
  short* Vt    = (short*)alloc((size_t)64 * 64 * 512 * 2);
  short* sc1   = (short*)alloc((size_t)4096 * 256 * 2);
  short* qkvt  = (short*)alloc((size_t)6 * 1536 * 512 * 2);
  short* wot   = (short*)alloc((size_t)6 * 512 * 512 * 2);
  short* w1t   = (short*)alloc((size_t)6 * 2048 * 512 * 2);
  short* w2t   = (short*)alloc((size_t)6 * 512 * 2048 * 2);
  short* ws1t  = (short*)alloc((size_t)256 * 512 * 2);
  short* woutT = (short*)alloc((size_t)32 * 512 * 2);

  prologue_kernel<<<26768, 256, 0, stream>>>(x, W_in, b_in, pe, h_bf, Wq, Wk, Wv, Wo, W1, W2,
                                             Ws1, Wout, qkvt, wot, w1t, w2t, ws1t, woutT);

  for (int l = 0; l < 6; ++l) {
    gemm_bt<5, 128, 128, 64><<<dim3(12, 32), 256, 0, stream>>>(
        h_bf, qkvt + (size_t)l * 786432, qh, nullptr, 4096, 1536, 512);
    vt_kernel<<<dim3(16, 2, 64), 256, 0, stream>>>(qh, Vt);
    smpv_kernel<<<dim3(32, 64), 256, 0, stream>>>(qh, Vt, Pbuf, ctxb);
    if (l == 0)
      wo_kl_kernel<1><<<dim3(24, 64), 256, 0, stream>>>(ctxb, wot + (size_t)l * 262144,
                                                        bo + l * 512, aout, Pbuf, assoc);
    else
      wo_kl_kernel<0><<<dim3(24, 64), 256, 0, stream>>>(ctxb, wot + (size_t)l * 262144,
                                                        bo + l * 512, aout, Pbuf, assoc);
    ln_kernel<<<1024, 256, 0, stream>>>(aout, ln1g + l * 512, ln1b + l * 512, h_bf);
    gemm_bt<2, 128, 128, 64><<<dim3(16, 32), 256, 0, stream>>>(
        h_bf, w1t + (size_t)l * 1048576, ff1b, b1 + l * 2048, 4096, 2048, 512);
    gemm_bt<4, 64, 64, 64><<<dim3(8, 64), 256, 0, stream>>>(
        ff1b, w2t + (size_t)l * 1048576, ff2, b2 + l * 512, 4096, 512, 2048);
    ln_kernel<<<1024, 256, 0, stream>>>(ff2, ln2g + l * 512, ln2b + l * 512, h_bf);
  }

  float* out = (float*)d_out;
  recon_mfma<<<32, 256, 0, stream>>>(h_bf, woutT, bout, out);
  gemm_bt<2, 128, 128, 64><<<dim3(2, 32), 256, 0, stream>>>(h_bf, ws1t, sc1, bs1,
                                                            4096, 256, 512);
  score2_kernel<<<1024, 256, 0, stream>>>(sc1, Ws2, bs2, assoc, out + 131072,
                                          out + 131072 + 4096);
}

// Round 15
// 731.961 us; speedup vs baseline: 1.1395x; 1.0204x over previous
//
#include <hip/hip_runtime.h>
#include <math.h>

typedef __attribute__((ext_vector_type(8))) short bf16x8;
typedef __attribute__((ext_vector_type(4))) float f32x4;

__device__ __forceinline__ short f2bf(float v) {
  union { float f; unsigned u; } x; x.f = v;
  unsigned r = x.u + 0x7fffu + ((x.u >> 16) & 1u);
  return (short)(r >> 16);
}

__device__ __forceinline__ float bf2f(unsigned short u) {
  union { unsigned u; float f; } x; x.u = ((unsigned)u) << 16;
  return x.f;
}

__device__ __forceinline__ void gld_lds16(const void* g, void* l) {
  __builtin_amdgcn_global_load_lds((const __attribute__((address_space(1))) void*)g,
                                   (__attribute__((address_space(3))) void*)l, 16, 0, 0);
}

// ---------------- mega prologue: embed + ALL weight transposes in one dispatch ----------------
__global__ __launch_bounds__(256) void prologue_kernel(
    const float* __restrict__ x, const float* __restrict__ W_in, const float* __restrict__ b_in,
    const float* __restrict__ pe, short* __restrict__ hbf,
    const float* __restrict__ Wq, const float* __restrict__ Wk, const float* __restrict__ Wv,
    const float* __restrict__ Wo, const float* __restrict__ W1, const float* __restrict__ W2,
    const float* __restrict__ Ws1, const float* __restrict__ Wout,
    short* __restrict__ qkvt, short* __restrict__ wot, short* __restrict__ w1t,
    short* __restrict__ w2t, short* __restrict__ ws1t, short* __restrict__ woutT) {
  __shared__ float t[32][33];
  const int tid = threadIdx.x;
  int idx = blockIdx.x;
  if (idx < 8192) {  // ---- embed: h_bf = bf16(x @ W_in + b_in + pe) ----
    int col = (idx & 1) * 256 + tid;
    int row = idx >> 1;
    int s = row & 511;
    float a = b_in[col] + pe[s * 512 + col];
    const float* xr = x + (size_t)row * 32;
#pragma unroll
    for (int k = 0; k < 32; k++) a += xr[k] * W_in[k * 512 + col];
    hbf[(size_t)row * 512 + col] = f2bf(a);
    return;
  }
  idx -= 8192;
  const float* src;
  short* dst;
  int R, C, cx, cy;
  if (idx < 4608) {  // qkv: 18 z x (16x16)
    int z = idx >> 8, rem = idx & 255;
    cx = rem & 15; cy = rem >> 4;
    int which = z / 6, l = z % 6;
    src = (which == 0 ? Wq : which == 1 ? Wk : Wv) + (size_t)l * 262144;
    dst = qkvt + (size_t)l * 786432 + (size_t)which * 262144;
    R = 512; C = 512;
  } else if (idx < 6144) {  // wo: 6 z x (16x16)
    int j = idx - 4608;
    int l = j >> 8, rem = j & 255;
    cx = rem & 15; cy = rem >> 4;
    src = Wo + (size_t)l * 262144; dst = wot + (size_t)l * 262144;
    R = 512; C = 512;
  } else if (idx < 12288) {  // w1: 6 z x (64x16)
    int j = idx - 6144;
    int l = j >> 10, rem = j & 1023;
    cx = rem & 63; cy = rem >> 6;
    src = W1 + (size_t)l * 1048576; dst = w1t + (size_t)l * 1048576;
    R = 512; C = 2048;
  } else if (idx < 18432) {  // w2: 6 z x (16x64)
    int j = idx - 12288;
    int l = j >> 10, rem = j & 1023;
    cx = rem & 15; cy = rem >> 4;
    src = W2 + (size_t)l * 1048576; dst = w2t + (size_t)l * 1048576;
    R = 2048; C = 512;
  } else if (idx < 18560) {  // ws1: (8x16)
    int j = idx - 18432;
    cx = j & 7; cy = j >> 3;
    src = Ws1; dst = ws1t; R = 512; C = 256;
  } else {  // wout: (1x16)
    int j = idx - 18560;
    cx = 0; cy = j;
    src = Wout; dst = woutT; R = 512; C = 32;
  }
  const int tx = tid & 31, ty = tid >> 5;
  const int c0 = cx * 32, r0 = cy * 32;
#pragma unroll
  for (int i = 0; i < 4; i++)
    t[ty + i * 8][tx] = src[(size_t)(r0 + ty + i * 8) * C + c0 + tx];
  __syncthreads();
#pragma unroll
  for (int i = 0; i < 4; i++)
    dst[(size_t)(c0 + ty + i * 8) * R + r0 + tx] = f2bf(t[tx][ty + i * 8]);
}

// ---------------- bf16 GEMM: A[M,K] x Bt[N,K]^T -> C[M,N] ----------------
// EPI: 2 bf16+bias+relu; 4 bf16+bias; 5 bf16 QKV->dense per-head layout (coalesced)
// BK=64 with BOTH-SIDES swizzle (rule #21): linear LDS dest + pre-swizzled GLOBAL source
// chunk + same XOR on fragment reads. r14 verified: bank conflicts = 0 (r4 unswizzled: 4.7M).
template <int EPI, int BM, int BN, int BK>
__global__ __launch_bounds__(256) void gemm_bt(const short* __restrict__ A,
                                               const short* __restrict__ Bt,
                                               short* __restrict__ Cb,
                                               const float* __restrict__ bias,
                                               int M, int N, int K) {
  __shared__ short As[BM * BK];
  __shared__ short Bs[BN * BK];
  const int tid = threadIdx.x;
  const int wid = tid >> 6;
  const int lane = tid & 63;
  const int m0 = blockIdx.y * BM;
  const int n0 = blockIdx.x * BN;
  constexpr int WR = BM / 2, WC = BN / 2, FI = WR / 16, FJ = WC / 16, KK = BK / 32;
  constexpr int CPR = BK / 8;
  constexpr int SM = CPR - 1;
  const int wr = (wid >> 1) * WR;
  const int wc = (wid & 1) * WC;

  f32x4 acc[FI][FJ];
#pragma unroll
  for (int i = 0; i < FI; i++)
#pragma unroll
    for (int j = 0; j < FJ; j++)
#pragma unroll
      for (int q = 0; q < 4; q++) acc[i][j][q] = 0.0f;

  const short* aBase = A + (size_t)m0 * K;
  const short* bBase = Bt + (size_t)n0 * K;
  constexpr int RPC = 512 / BK;
  constexpr int CA = BM / RPC;
  constexpr int CT = (BM + BN) / RPC;
  const int rowL = lane / CPR;
  const int colE = ((lane % CPR) ^ (rowL & SM)) * 8;
  const int g = lane >> 4;
  const int r16 = lane & 15;
  const int rsw = r16 & SM;

  for (int kt = 0; kt < K; kt += BK) {
    __syncthreads();
#pragma unroll
    for (int c = 0; c < CT / 4; ++c) {
      int s = c * 4 + wid;
      if (s < CA)
        gld_lds16(aBase + (size_t)(s * RPC + rowL) * K + kt + colE, As + s * 512);
      else
        gld_lds16(bBase + (size_t)((s - CA) * RPC + rowL) * K + kt + colE, Bs + (s - CA) * 512);
    }
    __syncthreads();
    bf16x8 af[FI][KK], bfr[FJ][KK];
#pragma unroll
    for (int i = 0; i < FI; i++)
#pragma unroll
      for (int kk = 0; kk < KK; kk++)
        af[i][kk] = *(const bf16x8*)&As[(wr + i * 16 + r16) * BK + (((kk * 4 + g) ^ rsw) * 8)];
#pragma unroll
    for (int j = 0; j < FJ; j++)
#pragma unroll
      for (int kk = 0; kk < KK; kk++)
        bfr[j][kk] = *(const bf16x8*)&Bs[(wc + j * 16 + r16) * BK + (((kk * 4 + g) ^ rsw) * 8)];
#pragma unroll
    for (int kk = 0; kk < KK; kk++)
#pragma unroll
      for (int i = 0; i < FI; i++)
#pragma unroll
        for (int j = 0; j < FJ; j++)
          acc[i][j] = __builtin_amdgcn_mfma_f32_16x16x32_bf16(af[i][kk], bfr[j][kk], acc[i][j], 0, 0, 0);
  }

  const int col16 = lane & 15;
  const int rowg = (lane >> 4) * 4;
#pragma unroll
  for (int i = 0; i < FI; i++) {
    int row = m0 + wr + i * 16 + rowg;
#pragma unroll
    for (int j = 0; j < FJ; j++) {
      int col = n0 + wc + j * 16 + col16;
      float bv = (EPI == 2 || EPI == 4) ? bias[col] : 0.0f;
#pragma unroll
      for (int q = 0; q < 4; q++) {
        float v = acc[i][j][q] + bv;
        if (EPI == 2) {
          v = fmaxf(v, 0.0f);
          Cb[(size_t)(row + q) * N + col] = f2bf(v);
        } else if (EPI == 5) {
          int rr = row + q;
          int sect = col >> 9, hh = (col >> 6) & 7, dk = col & 63;
          int bq = rr >> 9, tt = rr & 511;
          Cb[(((size_t)(sect * 64 + bq * 8 + hh)) * 512 + tt) * 64 + dk] = f2bf(v);
        } else {
          Cb[(size_t)(row + q) * N + col] = f2bf(v);
        }
      }
    }
  }
}

// ---------------- V transpose (dense layout): qh V-section -> Vt[bh][64 dk][512 t] ----------------
__global__ __launch_bounds__(256) void vt_kernel(const short* __restrict__ qh,
                                                 short* __restrict__ Vt) {
  __shared__ short t[32][34];
  const int bh = blockIdx.z;
  const int t0 = blockIdx.x * 32, d0 = blockIdx.y * 32;
  const int tx = threadIdx.x & 31, ty = threadIdx.x >> 5;
  const short* Vh = qh + (size_t)(128 + bh) * 512 * 64;
#pragma unroll
  for (int i = 0; i < 4; i++)
    t[ty + i * 8][tx] = Vh[(size_t)(t0 + ty + i * 8) * 64 + d0 + tx];
  __syncthreads();
#pragma unroll
  for (int i = 0; i < 4; i++)
    Vt[((size_t)bh * 64 + d0 + ty + i * 8) * 512 + t0 + tx] = t[tx][ty + i * 8];
}

// ---------------- fused scores+softmax+P dump+PV: per (bh, 16-query tile) ----------------
__global__ __launch_bounds__(256) void smpv_kernel(const short* __restrict__ qh,
                                                   const short* __restrict__ Vt,
                                                   short* __restrict__ P,
                                                   short* __restrict__ ctxb) {
  __shared__ short Pl[16 * 512];
  __shared__ float red0[4][16];
  __shared__ float red1[4][16];
  const int bh = blockIdx.y, b = bh >> 3, h = bh & 7;
  const int q0 = blockIdx.x * 16;
  const int tid = threadIdx.x;
  const int wid = tid >> 6, lane = tid & 63;
  const int r16 = lane & 15, g = lane >> 4;

  const short* Qh = qh + ((size_t)bh * 512) * 64;
  const short* Kh = qh + ((size_t)(64 + bh) * 512) * 64;

  const short* qp = Qh + (size_t)(q0 + r16) * 64 + g * 8;
  const bf16x8 qa0 = *(const bf16x8*)qp;
  const bf16x8 qa1 = *(const bf16x8*)(qp + 32);

  f32x4 acc[8];
#pragma unroll
  for (int tt = 0; tt < 8; ++tt) {
    const short* kp = Kh + (size_t)(wid * 128 + tt * 16 + r16) * 64 + g * 8;
    bf16x8 kb0 = *(const bf16x8*)kp;
    bf16x8 kb1 = *(const bf16x8*)(kp + 32);
    f32x4 c = {0.f, 0.f, 0.f, 0.f};
    c = __builtin_amdgcn_mfma_f32_16x16x32_bf16(qa0, kb0, c, 0, 0, 0);
    c = __builtin_amdgcn_mfma_f32_16x16x32_bf16(qa1, kb1, c, 0, 0, 0);
    acc[tt] = c;
  }

  float mx[4] = {-1e30f, -1e30f, -1e30f, -1e30f};
#pragma unroll
  for (int tt = 0; tt < 8; ++tt)
#pragma unroll
    for (int r = 0; r < 4; ++r) mx[r] = fmaxf(mx[r], acc[tt][r]);
#pragma unroll
  for (int r = 0; r < 4; ++r)
#pragma unroll
    for (int m = 8; m; m >>= 1) mx[r] = fmaxf(mx[r], __shfl_xor(mx[r], m, 16));
  if (r16 == 0) {
#pragma unroll
    for (int r = 0; r < 4; ++r) red0[wid][g * 4 + r] = mx[r];
  }
  __syncthreads();
#pragma unroll
  for (int r = 0; r < 4; ++r) {
    int q = g * 4 + r;
    mx[r] = fmaxf(fmaxf(red0[0][q], red0[1][q]), fmaxf(red0[2][q], red0[3][q]));
  }
  float sum[4] = {0.f, 0.f, 0.f, 0.f};
#pragma unroll
  for (int tt = 0; tt < 8; ++tt)
#pragma unroll
    for (int r = 0; r < 4; ++r) {
      float e = __expf((acc[tt][r] - mx[r]) * 0.125f);
      acc[tt][r] = e;
      sum[r] += e;
    }
#pragma unroll
  for (int r = 0; r < 4; ++r)
#pragma unroll
    for (int m = 8; m; m >>= 1) sum[r] += __shfl_xor(sum[r], m, 16);
  if (r16 == 0) {
#pragma unroll
    for (int r = 0; r < 4; ++r) red1[wid][g * 4 + r] = sum[r];
  }
  __syncthreads();

  char* plc = (char*)Pl;
#pragma unroll
  for (int r = 0; r < 4; ++r) {
    int q = g * 4 + r;
    float inv = 1.0f / (red1[0][q] + red1[1][q] + red1[2][q] + red1[3][q]);
    int swz = (q & 7) << 4;
#pragma unroll
    for (int tt = 0; tt < 8; ++tt)
      *(short*)(plc + q * 1024 + (((wid * 128 + tt * 16 + r16) * 2) ^ swz)) =
          f2bf(acc[tt][r] * inv);
  }
  __syncthreads();

  short* pg = P + ((size_t)bh * 512 + q0) * 512;
#pragma unroll
  for (int k = 0; k < 4; ++k) {
    int c = k * 256 + tid;
    int q = c >> 6;
    int tB = (c & 63) * 16;
    bf16x8 v = *(const bf16x8*)(plc + q * 1024 + (tB ^ ((q & 7) << 4)));
    *(bf16x8*)&pg[(size_t)q * 512 + (c & 63) * 8] = v;
  }

  f32x4 pacc0 = {0.f, 0.f, 0.f, 0.f}, pacc1 = {0.f, 0.f, 0.f, 0.f};
  const short* vb = Vt + (size_t)bh * 64 * 512 + (size_t)(wid * 16) * 512;
  const int rswz = (r16 & 7) << 4;
  for (int kt = 0; kt < 512; kt += 64) {
    bf16x8 af0 = *(const bf16x8*)(plc + r16 * 1024 + (((kt + g * 8) * 2) ^ rswz));
    bf16x8 af1 = *(const bf16x8*)(plc + r16 * 1024 + (((kt + 32 + g * 8) * 2) ^ rswz));
    bf16x8 b0 = *(const bf16x8*)&vb[(size_t)r16 * 512 + kt + g * 8];
    bf16x8 b1 = *(const bf16x8*)&vb[(size_t)r16 * 512 + kt + 32 + g * 8];
    pacc0 = __builtin_amdgcn_mfma_f32_16x16x32_bf16(af0, b0, pacc0, 0, 0, 0);
    pacc1 = __builtin_amdgcn_mfma_f32_16x16x32_bf16(af1, b1, pacc1, 0, 0, 0);
  }
  const int col = h * 64 + wid * 16 + r16;
#pragma unroll
  for (int q = 0; q < 4; ++q)
    ctxb[(size_t)(b * 512 + q0 + g * 4 + q) * 512 + col] = f2bf(pacc0[q] + pacc1[q]);
}

// ---------------- grid-union: Wo 64x64 GEMM BK=64 swizzled (x<8) + KL (x>=8) ----------------
template <int FIRST>
__global__ __launch_bounds__(256) void wo_kl_kernel(const short* __restrict__ A,
                                                    const short* __restrict__ Bt,
                                                    const float* __restrict__ bias,
                                                    short* __restrict__ aout,
                                                    const short* __restrict__ P,
                                                    float* __restrict__ assoc) {
  __shared__ short As[64 * 64];
  __shared__ short Bs[64 * 64];
  const int tid = threadIdx.x;
  const int wid = tid >> 6, lane = tid & 63;
  if (blockIdx.x < 8) {
    // Wo gemm: M=4096 N=512 K=512, BM=BN=64, BK=64, both-sides swizzle (r14-verified)
    const int m0 = blockIdx.y * 64;
    const int n0 = blockIdx.x * 64;
    const int wr = (wid >> 1) * 32;
    const int wc = (wid & 1) * 32;
    f32x4 acc[2][2];
#pragma unroll
    for (int i = 0; i < 2; i++)
#pragma unroll
      for (int j = 0; j < 2; j++)
#pragma unroll
        for (int q = 0; q < 4; q++) acc[i][j][q] = 0.0f;
    const short* aBase = A + (size_t)m0 * 512;
    const short* bBase = Bt + (size_t)n0 * 512;
    const int rowL = lane >> 3;                         // 8 rows/call (1024B / 128B row)
    const int colE = ((lane & 7) ^ (rowL & 7)) * 8;     // pre-swizzled global chunk
    const int g = lane >> 4;
    const int r16 = lane & 15;
    const int rsw = r16 & 7;
    for (int kt = 0; kt < 512; kt += 64) {
      __syncthreads();
#pragma unroll
      for (int c = 0; c < 4; ++c) {
        int s = c * 4 + wid;
        if (s < 8)
          gld_lds16(aBase + (size_t)(s * 8 + rowL) * 512 + kt + colE, As + s * 512);
        else
          gld_lds16(bBase + (size_t)((s - 8) * 8 + rowL) * 512 + kt + colE, Bs + (s - 8) * 512);
      }
      __syncthreads();
      bf16x8 af[2][2], bfr[2][2];
#pragma unroll
      for (int i = 0; i < 2; i++)
#pragma unroll
        for (int kk = 0; kk < 2; kk++)
          af[i][kk] = *(const bf16x8*)&As[(wr + i * 16 + r16) * 64 + (((kk * 4 + g) ^ rsw) * 8)];
#pragma unroll
      for (int j = 0; j < 2; j++)
#pragma unroll
        for (int kk = 0; kk < 2; kk++)
          bfr[j][kk] = *(const bf16x8*)&Bs[(wc + j * 16 + r16) * 64 + (((kk * 4 + g) ^ rsw) * 8)];
#pragma unroll
      for (int kk = 0; kk < 2; kk++)
#pragma unroll
        for (int i = 0; i < 2; i++)
#pragma unroll
          for (int j = 0; j < 2; j++)
            acc[i][j] = __builtin_amdgcn_mfma_f32_16x16x32_bf16(af[i][kk], bfr[j][kk], acc[i][j], 0, 0, 0);
    }
    const int col16 = lane & 15;
    const int rowg = (lane >> 4) * 4;
#pragma unroll
    for (int i = 0; i < 2; i++) {
      int row = m0 + wr + i * 16 + rowg;
#pragma unroll
      for (int j = 0; j < 2; j++) {
        int col = n0 + wc + j * 16 + col16;
        float bv = bias[col];
#pragma unroll
        for (int q = 0; q < 4; q++)
          aout[(size_t)(row + q) * 512 + col] = f2bf(acc[i][j][q] + bv);
      }
    }
  } else {
    const int kb = (blockIdx.x - 8) * 64 + blockIdx.y;
    const int row = kb * 4 + wid;
    const int b = row >> 9, q = row & 511;
    const float prior = 1.0f / 512.0f + 1e-8f;
    float hs[8] = {0.f, 0.f, 0.f, 0.f, 0.f, 0.f, 0.f, 0.f};
#pragma unroll
    for (int h = 0; h < 8; ++h) {
      bf16x8 v = *(const bf16x8*)&P[(((size_t)(b * 8 + h)) * 512 + q) * 512 + lane * 8];
#pragma unroll
      for (int k = 0; k < 8; ++k) hs[k] += bf2f((unsigned short)v[k]);
    }
    float s = 0.f;
#pragma unroll
    for (int k = 0; k < 8; ++k) {
      float a = hs[k] * 0.125f + 1e-8f;
      s += a * __logf(a / prior);
    }
#pragma unroll
    for (int m = 32; m; m >>= 1) s += __shfl_xor(s, m, 64);
    if (lane == 0) assoc[row] = FIRST ? s : (assoc[row] + s);
  }
}

// ---------------- layernorm in-place on bf16 residual stream ----------------
__global__ __launch_bounds__(256) void ln_kernel(const short* __restrict__ res,
                                                 const float* __restrict__ g,
                                                 const float* __restrict__ bta,
                                                 short* __restrict__ hbf) {
  const int wid = threadIdx.x >> 6, lane = threadIdx.x & 63;
  const size_t row = (size_t)blockIdx.x * 4 + wid;
  bf16x8 hv = *(const bf16x8*)&hbf[row * 512 + lane * 8];
  bf16x8 rv = *(const bf16x8*)&res[row * 512 + lane * 8];
  float v[8], s = 0.f, s2 = 0.f;
#pragma unroll
  for (int i = 0; i < 8; i++) {
    v[i] = bf2f((unsigned short)hv[i]) + bf2f((unsigned short)rv[i]);
    s += v[i];
    s2 += v[i] * v[i];
  }
#pragma unroll
  for (int m = 32; m; m >>= 1) {
    s += __shfl_xor(s, m, 64);
    s2 += __shfl_xor(s2, m, 64);
  }
  float mu = s * (1.0f / 512.0f);
  float var = s2 * (1.0f / 512.0f) - mu * mu;
  float rs = rsqrtf(var + 1e-5f);
  const float* gp = g + lane * 8;
  const float* bp = bta + lane * 8;
  bf16x8 ob;
#pragma unroll
  for (int i = 0; i < 8; i++) ob[i] = f2bf((v[i] - mu) * rs * gp[i] + bp[i]);
  *(bf16x8*)&hbf[row * 512 + lane * 8] = ob;
}

// ---------------- tail union: score1 GEMM (x<2) + recon MFMA (x==2) ----------------
__global__ __launch_bounds__(256) void tail_kernel(const short* __restrict__ hbf,
                                                   const short* __restrict__ ws1t,
                                                   const float* __restrict__ bs1,
                                                   short* __restrict__ sc1,
                                                   const short* __restrict__ WoutT,
                                                   const float* __restrict__ bout,
                                                   float* __restrict__ out) {
  __shared__ short As[128 * 64];
  __shared__ short Bs[128 * 64];
  const int tid = threadIdx.x;
  const int wid = tid >> 6, lane = tid & 63;
  const int g = lane >> 4, r16 = lane & 15;
  if (blockIdx.x < 2) {
    // score1: sc1[4096,256] = relu(h_bf @ ws1t^T + bs1), BM=BN=128, BK=64 swizzled
    const int m0 = blockIdx.y * 128;
    const int n0 = blockIdx.x * 128;
    const int wr = (wid >> 1) * 64;
    const int wc = (wid & 1) * 64;
    f32x4 acc[4][4];
#pragma unroll
    for (int i = 0; i < 4; i++)
#pragma unroll
      for (int j = 0; j < 4; j++)
#pragma unroll
        for (int q = 0; q < 4; q++) acc[i][j][q] = 0.0f;
    const short* aBase = hbf + (size_t)m0 * 512;
    const short* bBase = ws1t + (size_t)n0 * 512;
    const int rowL = lane >> 3;
    const int colE = ((lane & 7) ^ (rowL & 7)) * 8;
    const int rsw = r16 & 7;
    for (int kt = 0; kt < 512; kt += 64) {
      __syncthreads();
#pragma unroll
      for (int c = 0; c < 8; ++c) {
        int s = c * 4 + wid;
        if (s < 16)
          gld_lds16(aBase + (size_t)(s * 8 + rowL) * 512 + kt + colE, As + s * 512);
        else
          gld_lds16(bBase + (size_t)((s - 16) * 8 + rowL) * 512 + kt + colE, Bs + (s - 16) * 512);
      }
      __syncthreads();
      bf16x8 af[4][2], bfr[4][2];
#pragma unroll
      for (int i = 0; i < 4; i++)
#pragma unroll
        for (int kk = 0; kk < 2; kk++)
          af[i][kk] = *(const bf16x8*)&As[(wr + i * 16 + r16) * 64 + (((kk * 4 + g) ^ rsw) * 8)];
#pragma unroll
      for (int j = 0; j < 4; j++)
#pragma unroll
        for (int kk = 0; kk < 2; kk++)
          bfr[j][kk] = *(const bf16x8*)&Bs[(wc + j * 16 + r16) * 64 + (((kk * 4 + g) ^ rsw) * 8)];
#pragma unroll
      for (int kk = 0; kk < 2; kk++)
#pragma unroll
        for (int i = 0; i < 4; i++)
#pragma unroll
          for (int j = 0; j < 4; j++)
            acc[i][j] = __builtin_amdgcn_mfma_f32_16x16x32_bf16(af[i][kk], bfr[j][kk], acc[i][j], 0, 0, 0);
    }
    const int rowg = g * 4;
#pragma unroll
    for (int i = 0; i < 4; i++) {
      int row = m0 + wr + i * 16 + rowg;
#pragma unroll
      for (int j = 0; j < 4; j++) {
        int col = n0 + wc + j * 16 + r16;
        float bv = bs1[col];
#pragma unroll
        for (int q = 0; q < 4; q++)
          sc1[(size_t)(row + q) * 256 + col] = f2bf(fmaxf(acc[i][j][q] + bv, 0.0f));
      }
    }
  } else {
    // recon: out[4096,32] = h_bf @ WoutT^T + bout (per-wave 32 rows)
    const int wbase = blockIdx.y * 128 + wid * 32;
    const int kg = g * 8;
    f32x4 acc[2][2];
#pragma unroll
    for (int i = 0; i < 2; i++)
#pragma unroll
      for (int j = 0; j < 2; j++)
#pragma unroll
        for (int q = 0; q < 4; q++) acc[i][j][q] = 0.0f;
    for (int kt = 0; kt < 512; kt += 32) {
      bf16x8 af[2], bfr[2];
#pragma unroll
      for (int i = 0; i < 2; i++)
        af[i] = *(const bf16x8*)&hbf[(size_t)(wbase + i * 16 + r16) * 512 + kt + kg];
#pragma unroll
      for (int j = 0; j < 2; j++)
        bfr[j] = *(const bf16x8*)&WoutT[(size_t)(j * 16 + r16) * 512 + kt + kg];
#pragma unroll
      for (int i = 0; i < 2; i++)
#pragma unroll
        for (int j = 0; j < 2; j++)
          acc[i][j] = __builtin_amdgcn_mfma_f32_16x16x32_bf16(af[i], bfr[j], acc[i][j], 0, 0, 0);
    }
    const int rowg = g * 4;
#pragma unroll
    for (int i = 0; i < 2; i++)
#pragma unroll
      for (int j = 0; j < 2; j++) {
        int col = j * 16 + r16;
#pragma unroll
        for (int q = 0; q < 4; q++)
          out[(size_t)(wbase + i * 16 + rowg + q) * 32 + col] = acc[i][j][q] + bout[col];
      }
  }
}

// ---------------- score stage 2 + assoc output ----------------
__global__ __launch_bounds__(256) void score2_kernel(const short* __restrict__ s1,
                                                     const float* __restrict__ Ws2,
                                                     const float* __restrict__ bs2,
                                                     const float* __restrict__ assoc,
                                                     float* __restrict__ outScore,
                                                     float* __restrict__ outAssoc) {
  const int wid = threadIdx.x >> 6, lane = threadIdx.x & 63;
  const int row = blockIdx.x * 4 + wid;
  const short* rp = &s1[(size_t)row * 256 + lane * 4];
  float d = 0.f;
#pragma unroll
  for (int e = 0; e < 4; e++) d += bf2f((unsigned short)rp[e]) * Ws2[lane * 4 + e];
#pragma unroll
  for (int m = 32; m; m >>= 1) d += __shfl_xor(d, m, 64);
  if (lane == 0) {
    outScore[row] = 1.f / (1.f + __expf(-(d + bs2[0])));
    outAssoc[row] = assoc[row] * (1.0f / 6.0f);
  }
}

extern "C" void kernel_launch(void* const* d_in, const int* in_sizes, int n_in,
                              void* d_out, int out_size, void* d_ws, size_t ws_size,
                              hipStream_t stream) {
  const float* x    = (const float*)d_in[0];
  const float* W_in = (const float*)d_in[1];
  const float* b_in = (const float*)d_in[2];
  const float* pe   = (const float*)d_in[3];
  const float* Wq   = (const float*)d_in[4];
  const float* Wk   = (const float*)d_in[5];
  const float* Wv   = (const float*)d_in[6];
  const float* Wo   = (const float*)d_in[7];
  const float* bo   = (const float*)d_in[8];
  const float* W1   = (const float*)d_in[9];
  const float* b1   = (const float*)d_in[10];
  const float* W2   = (const float*)d_in[11];
  const float* b2   = (const float*)d_in[12];
  const float* ln1g = (const float*)d_in[13];
  const float* ln1b = (const float*)d_in[14];
  const float* ln2g = (const float*)d_in[15];
  const float* ln2b = (const float*)d_in[16];
  const float* Wout = (const float*)d_in[17];
  const float* bout = (const float*)d_in[18];
  const float* Ws1  = (const float*)d_in[19];
  const float* bs1  = (const float*)d_in[20];
  const float* Ws2  = (const float*)d_in[21];
  const float* bs2  = (const float*)d_in[22];

  char* p = (char*)d_ws;
  auto alloc = [&](size_t bytes) {
    void* r = (void*)p;
    p += (bytes + 255) & ~(size_t)255;
    return r;
  };
  short* h_bf  = (short*)alloc((size_t)4096 * 512 * 2);
  short* qh    = (short*)alloc((size_t)4096 * 1536 * 2);
  short* aout  = (short*)alloc((size_t)4096 * 512 * 2);
  short* ctxb  = (short*)alloc((size_t)4096 * 512 * 2);
  short* ff1b  = (short*)alloc((size_t)4096 * 2048 * 2);
  short* ff2   = (short*)alloc((size_t)4096 * 512 * 2);
  float* assoc = (float*)alloc((size_t)4096 * 4);
  short* Pbuf  = (short*)alloc((size_t)64 * 512 * 512 * 2);
  short* Vt    = (short*)alloc((size_t)64 * 64 * 512 * 2);
  short* sc1   = (short*)alloc((size_t)4096 * 256 * 2);
  short* qkvt  = (short*)alloc((size_t)6 * 1536 * 512 * 2);
  short* wot   = (short*)alloc((size_t)6 * 512 * 512 * 2);
  short* w1t   = (short*)alloc((size_t)6 * 2048 * 512 * 2);
  short* w2t   = (short*)alloc((size_t)6 * 512 * 2048 * 2);
  short* ws1t  = (short*)alloc((size_t)256 * 512 * 2);
  short* woutT = (short*)alloc((size_t)32 * 512 * 2);

  prologue_kernel<<<26768, 256, 0, stream>>>(x, W_in, b_in, pe, h_bf, Wq, Wk, Wv, Wo, W1, W2,
                                             Ws1, Wout, qkvt, wot, w1t, w2t, ws1t, woutT);

  for (int l = 0; l < 6; ++l) {
    gemm_bt<5, 128, 128, 64><<<dim3(12, 32), 256, 0, stream>>>(
        h_bf, qkvt + (size_t)l * 786432, qh, nullptr, 4096, 1536, 512);
    vt_kernel<<<dim3(16, 2, 64), 256, 0, stream>>>(qh, Vt);
    smpv_kernel<<<dim3(32, 64), 256, 0, stream>>>(qh, Vt, Pbuf, ctxb);
    if (l == 0)
      wo_kl_kernel<1><<<dim3(24, 64), 256, 0, stream>>>(ctxb, wot + (size_t)l * 262144,
                                                        bo + l * 512, aout, Pbuf, assoc);
    else
      wo_kl_kernel<0><<<dim3(24, 64), 256, 0, stream>>>(ctxb, wot + (size_t)l * 262144,
                                                        bo + l * 512, aout, Pbuf, assoc);
    ln_kernel<<<1024, 256, 0, stream>>>(aout, ln1g + l * 512, ln1b + l * 512, h_bf);
    gemm_bt<2, 128, 128, 64><<<dim3(16, 32), 256, 0, stream>>>(
        h_bf, w1t + (size_t)l * 1048576, ff1b, b1 + l * 2048, 4096, 2048, 512);
    gemm_bt<4, 64, 64, 64><<<dim3(8, 64), 256, 0, stream>>>(
        ff1b, w2t + (size_t)l * 1048576, ff2, b2 + l * 512, 4096, 512, 2048);
    ln_kernel<<<1024, 256, 0, stream>>>(ff2, ln2g + l * 512, ln2b + l * 512, h_bf);
  }

  float* out = (float*)d_out;
  tail_kernel<<<dim3(3, 32), 256, 0, stream>>>(h_bf, ws1t, bs1, sc1, woutT, bout, out);
  score2_kernel<<<1024, 256, 0, stream>>>(sc1, Ws2, bs2, assoc, out + 131072,
                                          out + 131072 + 4096);
}

// Round 16
// 726.072 us; speedup vs baseline: 1.1488x; 1.0081x over previous
//
#include <hip/hip_runtime.h>
#include <math.h>

typedef __attribute__((ext_vector_type(8))) short bf16x8;
typedef __attribute__((ext_vector_type(4))) float f32x4;

__device__ __forceinline__ short f2bf(float v) {
  union { float f; unsigned u; } x; x.f = v;
  unsigned r = x.u + 0x7fffu + ((x.u >> 16) & 1u);
  return (short)(r >> 16);
}

__device__ __forceinline__ float bf2f(unsigned short u) {
  union { unsigned u; float f; } x; x.u = ((unsigned)u) << 16;
  return x.f;
}

__device__ __forceinline__ void gld_lds16(const void* g, void* l) {
  __builtin_amdgcn_global_load_lds((const __attribute__((address_space(1))) void*)g,
                                   (__attribute__((address_space(3))) void*)l, 16, 0, 0);
}

// ---------------- mega prologue: embed + ALL weight transposes in one dispatch ----------------
__global__ __launch_bounds__(256) void prologue_kernel(
    const float* __restrict__ x, const float* __restrict__ W_in, const float* __restrict__ b_in,
    const float* __restrict__ pe, short* __restrict__ hbf,
    const float* __restrict__ Wq, const float* __restrict__ Wk, const float* __restrict__ Wv,
    const float* __restrict__ Wo, const float* __restrict__ W1, const float* __restrict__ W2,
    const float* __restrict__ Ws1, const float* __restrict__ Wout,
    short* __restrict__ qkvt, short* __restrict__ wot, short* __restrict__ w1t,
    short* __restrict__ w2t, short* __restrict__ ws1t, short* __restrict__ woutT) {
  __shared__ float t[32][33];
  const int tid = threadIdx.x;
  int idx = blockIdx.x;
  if (idx < 8192) {  // ---- embed: h_bf = bf16(x @ W_in + b_in + pe) ----
    int col = (idx & 1) * 256 + tid;
    int row = idx >> 1;
    int s = row & 511;
    float a = b_in[col] + pe[s * 512 + col];
    const float* xr = x + (size_t)row * 32;
#pragma unroll
    for (int k = 0; k < 32; k++) a += xr[k] * W_in[k * 512 + col];
    hbf[(size_t)row * 512 + col] = f2bf(a);
    return;
  }
  idx -= 8192;
  const float* src;
  short* dst;
  int R, C, cx, cy;
  if (idx < 4608) {  // qkv: 18 z x (16x16)
    int z = idx >> 8, rem = idx & 255;
    cx = rem & 15; cy = rem >> 4;
    int which = z / 6, l = z % 6;
    src = (which == 0 ? Wq : which == 1 ? Wk : Wv) + (size_t)l * 262144;
    dst = qkvt + (size_t)l * 786432 + (size_t)which * 262144;
    R = 512; C = 512;
  } else if (idx < 6144) {  // wo: 6 z x (16x16)
    int j = idx - 4608;
    int l = j >> 8, rem = j & 255;
    cx = rem & 15; cy = rem >> 4;
    src = Wo + (size_t)l * 262144; dst = wot + (size_t)l * 262144;
    R = 512; C = 512;
  } else if (idx < 12288) {  // w1: 6 z x (64x16)
    int j = idx - 6144;
    int l = j >> 10, rem = j & 1023;
    cx = rem & 63; cy = rem >> 6;
    src = W1 + (size_t)l * 1048576; dst = w1t + (size_t)l * 1048576;
    R = 512; C = 2048;
  } else if (idx < 18432) {  // w2: 6 z x (16x64)
    int j = idx - 12288;
    int l = j >> 10, rem = j & 1023;
    cx = rem & 15; cy = rem >> 4;
    src = W2 + (size_t)l * 1048576; dst = w2t + (size_t)l * 1048576;
    R = 2048; C = 512;
  } else if (idx < 18560) {  // ws1: (8x16)
    int j = idx - 18432;
    cx = j & 7; cy = j >> 3;
    src = Ws1; dst = ws1t; R = 512; C = 256;
  } else {  // wout: (1x16)
    int j = idx - 18560;
    cx = 0; cy = j;
    src = Wout; dst = woutT; R = 512; C = 32;
  }
  const int tx = tid & 31, ty = tid >> 5;
  const int c0 = cx * 32, r0 = cy * 32;
#pragma unroll
  for (int i = 0; i < 4; i++)
    t[ty + i * 8][tx] = src[(size_t)(r0 + ty + i * 8) * C + c0 + tx];
  __syncthreads();
#pragma unroll
  for (int i = 0; i < 4; i++)
    dst[(size_t)(c0 + ty + i * 8) * R + r0 + tx] = f2bf(t[tx][ty + i * 8]);
}

// ---------------- bf16 GEMM: A[M,K] x Bt[N,K]^T -> C[M,N] ----------------
// EPI: 2 bf16+bias+relu; 4 bf16+bias; 5 bf16 QKV->dense per-head layout (coalesced)
// BK=64 with BOTH-SIDES swizzle (rule #21): r14 verified bank conflicts = 0.
template <int EPI, int BM, int BN, int BK>
__global__ __launch_bounds__(256) void gemm_bt(const short* __restrict__ A,
                                               const short* __restrict__ Bt,
                                               short* __restrict__ Cb,
                                               const float* __restrict__ bias,
                                               int M, int N, int K) {
  __shared__ short As[BM * BK];
  __shared__ short Bs[BN * BK];
  const int tid = threadIdx.x;
  const int wid = tid >> 6;
  const int lane = tid & 63;
  const int m0 = blockIdx.y * BM;
  const int n0 = blockIdx.x * BN;
  constexpr int WR = BM / 2, WC = BN / 2, FI = WR / 16, FJ = WC / 16, KK = BK / 32;
  constexpr int CPR = BK / 8;
  constexpr int SM = CPR - 1;
  const int wr = (wid >> 1) * WR;
  const int wc = (wid & 1) * WC;

  f32x4 acc[FI][FJ];
#pragma unroll
  for (int i = 0; i < FI; i++)
#pragma unroll
    for (int j = 0; j < FJ; j++)
#pragma unroll
      for (int q = 0; q < 4; q++) acc[i][j][q] = 0.0f;

  const short* aBase = A + (size_t)m0 * K;
  const short* bBase = Bt + (size_t)n0 * K;
  constexpr int RPC = 512 / BK;
  constexpr int CA = BM / RPC;
  constexpr int CT = (BM + BN) / RPC;
  const int rowL = lane / CPR;
  const int colE = ((lane % CPR) ^ (rowL & SM)) * 8;
  const int g = lane >> 4;
  const int r16 = lane & 15;
  const int rsw = r16 & SM;

  for (int kt = 0; kt < K; kt += BK) {
    __syncthreads();
#pragma unroll
    for (int c = 0; c < CT / 4; ++c) {
      int s = c * 4 + wid;
      if (s < CA)
        gld_lds16(aBase + (size_t)(s * RPC + rowL) * K + kt + colE, As + s * 512);
      else
        gld_lds16(bBase + (size_t)((s - CA) * RPC + rowL) * K + kt + colE, Bs + (s - CA) * 512);
    }
    __syncthreads();
    bf16x8 af[FI][KK], bfr[FJ][KK];
#pragma unroll
    for (int i = 0; i < FI; i++)
#pragma unroll
      for (int kk = 0; kk < KK; kk++)
        af[i][kk] = *(const bf16x8*)&As[(wr + i * 16 + r16) * BK + (((kk * 4 + g) ^ rsw) * 8)];
#pragma unroll
    for (int j = 0; j < FJ; j++)
#pragma unroll
      for (int kk = 0; kk < KK; kk++)
        bfr[j][kk] = *(const bf16x8*)&Bs[(wc + j * 16 + r16) * BK + (((kk * 4 + g) ^ rsw) * 8)];
#pragma unroll
    for (int kk = 0; kk < KK; kk++)
#pragma unroll
      for (int i = 0; i < FI; i++)
#pragma unroll
        for (int j = 0; j < FJ; j++)
          acc[i][j] = __builtin_amdgcn_mfma_f32_16x16x32_bf16(af[i][kk], bfr[j][kk], acc[i][j], 0, 0, 0);
  }

  const int col16 = lane & 15;
  const int rowg = (lane >> 4) * 4;
#pragma unroll
  for (int i = 0; i < FI; i++) {
    int row = m0 + wr + i * 16 + rowg;
#pragma unroll
    for (int j = 0; j < FJ; j++) {
      int col = n0 + wc + j * 16 + col16;
      float bv = (EPI == 2 || EPI == 4) ? bias[col] : 0.0f;
#pragma unroll
      for (int q = 0; q < 4; q++) {
        float v = acc[i][j][q] + bv;
        if (EPI == 2) {
          v = fmaxf(v, 0.0f);
          Cb[(size_t)(row + q) * N + col] = f2bf(v);
        } else if (EPI == 5) {
          int rr = row + q;
          int sect = col >> 9, hh = (col >> 6) & 7, dk = col & 63;
          int bq = rr >> 9, tt = rr & 511;
          Cb[(((size_t)(sect * 64 + bq * 8 + hh)) * 512 + tt) * 64 + dk] = f2bf(v);
        } else {
          Cb[(size_t)(row + q) * N + col] = f2bf(v);
        }
      }
    }
  }
}

// ---------------- V transpose (dense layout): qh V-section -> Vt[bh][64 dk][512 t] ----------------
__global__ __launch_bounds__(256) void vt_kernel(const short* __restrict__ qh,
                                                 short* __restrict__ Vt) {
  __shared__ short t[32][34];
  const int bh = blockIdx.z;
  const int t0 = blockIdx.x * 32, d0 = blockIdx.y * 32;
  const int tx = threadIdx.x & 31, ty = threadIdx.x >> 5;
  const short* Vh = qh + (size_t)(128 + bh) * 512 * 64;
#pragma unroll
  for (int i = 0; i < 4; i++)
    t[ty + i * 8][tx] = Vh[(size_t)(t0 + ty + i * 8) * 64 + d0 + tx];
  __syncthreads();
#pragma unroll
  for (int i = 0; i < 4; i++)
    Vt[((size_t)bh * 64 + d0 + ty + i * 8) * 512 + t0 + tx] = t[tx][ty + i * 8];
}

// ---------------- fused scores+softmax+P dump+PV: per (bh, 16-query tile) ----------------
// XCD-aware swizzle (T1): default (q fastest) grid gives each XCD q-tiles of ALL 64 bh ->
// 8MB K+V working set > 4MB L2 -> thrash (FETCH 34.9MB measured r15). Decode so each XCD
// owns 8 bh (1MB, L2-resident): K/V misses on the dependent QK chain become L2 hits.
__global__ __launch_bounds__(256) void smpv_kernel(const short* __restrict__ qh,
                                                   const short* __restrict__ Vt,
                                                   short* __restrict__ P,
                                                   short* __restrict__ ctxb) {
  __shared__ short Pl[16 * 512];
  __shared__ float red0[4][16];
  __shared__ float red1[4][16];
  const int id = blockIdx.x;
  const int xcd = id & 7, slot = id >> 3;
  const int bh = xcd * 8 + (slot >> 5), b = bh >> 3, h = bh & 7;
  const int q0 = (slot & 31) * 16;
  const int tid = threadIdx.x;
  const int wid = tid >> 6, lane = tid & 63;
  const int r16 = lane & 15, g = lane >> 4;

  const short* Qh = qh + ((size_t)bh * 512) * 64;
  const short* Kh = qh + ((size_t)(64 + bh) * 512) * 64;

  const short* qp = Qh + (size_t)(q0 + r16) * 64 + g * 8;
  const bf16x8 qa0 = *(const bf16x8*)qp;
  const bf16x8 qa1 = *(const bf16x8*)(qp + 32);

  f32x4 acc[8];
#pragma unroll
  for (int tt = 0; tt < 8; ++tt) {
    const short* kp = Kh + (size_t)(wid * 128 + tt * 16 + r16) * 64 + g * 8;
    bf16x8 kb0 = *(const bf16x8*)kp;
    bf16x8 kb1 = *(const bf16x8*)(kp + 32);
    f32x4 c = {0.f, 0.f, 0.f, 0.f};
    c = __builtin_amdgcn_mfma_f32_16x16x32_bf16(qa0, kb0, c, 0, 0, 0);
    c = __builtin_amdgcn_mfma_f32_16x16x32_bf16(qa1, kb1, c, 0, 0, 0);
    acc[tt] = c;
  }

  float mx[4] = {-1e30f, -1e30f, -1e30f, -1e30f};
#pragma unroll
  for (int tt = 0; tt < 8; ++tt)
#pragma unroll
    for (int r = 0; r < 4; ++r) mx[r] = fmaxf(mx[r], acc[tt][r]);
#pragma unroll
  for (int r = 0; r < 4; ++r)
#pragma unroll
    for (int m = 8; m; m >>= 1) mx[r] = fmaxf(mx[r], __shfl_xor(mx[r], m, 16));
  if (r16 == 0) {
#pragma unroll
    for (int r = 0; r < 4; ++r) red0[wid][g * 4 + r] = mx[r];
  }
  __syncthreads();
#pragma unroll
  for (int r = 0; r < 4; ++r) {
    int q = g * 4 + r;
    mx[r] = fmaxf(fmaxf(red0[0][q], red0[1][q]), fmaxf(red0[2][q], red0[3][q]));
  }
  float sum[4] = {0.f, 0.f, 0.f, 0.f};
#pragma unroll
  for (int tt = 0; tt < 8; ++tt)
#pragma unroll
    for (int r = 0; r < 4; ++r) {
      float e = __expf((acc[tt][r] - mx[r]) * 0.125f);
      acc[tt][r] = e;
      sum[r] += e;
    }
#pragma unroll
  for (int r = 0; r < 4; ++r)
#pragma unroll
    for (int m = 8; m; m >>= 1) sum[r] += __shfl_xor(sum[r], m, 16);
  if (r16 == 0) {
#pragma unroll
    for (int r = 0; r < 4; ++r) red1[wid][g * 4 + r] = sum[r];
  }
  __syncthreads();

  char* plc = (char*)Pl;
#pragma unroll
  for (int r = 0; r < 4; ++r) {
    int q = g * 4 + r;
    float inv = 1.0f / (red1[0][q] + red1[1][q] + red1[2][q] + red1[3][q]);
    int swz = (q & 7) << 4;
#pragma unroll
    for (int tt = 0; tt < 8; ++tt)
      *(short*)(plc + q * 1024 + (((wid * 128 + tt * 16 + r16) * 2) ^ swz)) =
          f2bf(acc[tt][r] * inv);
  }
  __syncthreads();

  short* pg = P + ((size_t)bh * 512 + q0) * 512;
#pragma unroll
  for (int k = 0; k < 4; ++k) {
    int c = k * 256 + tid;
    int q = c >> 6;
    int tB = (c & 63) * 16;
    bf16x8 v = *(const bf16x8*)(plc + q * 1024 + (tB ^ ((q & 7) << 4)));
    *(bf16x8*)&pg[(size_t)q * 512 + (c & 63) * 8] = v;
  }

  f32x4 pacc0 = {0.f, 0.f, 0.f, 0.f}, pacc1 = {0.f, 0.f, 0.f, 0.f};
  const short* vb = Vt + (size_t)bh * 64 * 512 + (size_t)(wid * 16) * 512;
  const int rswz = (r16 & 7) << 4;
  for (int kt = 0; kt < 512; kt += 64) {
    bf16x8 af0 = *(const bf16x8*)(plc + r16 * 1024 + (((kt + g * 8) * 2) ^ rswz));
    bf16x8 af1 = *(const bf16x8*)(plc + r16 * 1024 + (((kt + 32 + g * 8) * 2) ^ rswz));
    bf16x8 b0 = *(const bf16x8*)&vb[(size_t)r16 * 512 + kt + g * 8];
    bf16x8 b1 = *(const bf16x8*)&vb[(size_t)r16 * 512 + kt + 32 + g * 8];
    pacc0 = __builtin_amdgcn_mfma_f32_16x16x32_bf16(af0, b0, pacc0, 0, 0, 0);
    pacc1 = __builtin_amdgcn_mfma_f32_16x16x32_bf16(af1, b1, pacc1, 0, 0, 0);
  }
  const int col = h * 64 + wid * 16 + r16;
#pragma unroll
  for (int q = 0; q < 4; ++q)
    ctxb[(size_t)(b * 512 + q0 + g * 4 + q) * 512 + col] = f2bf(pacc0[q] + pacc1[q]);
}

// ---------------- grid-union: Wo 64x64 GEMM BK=64 swizzled (x<8) + KL (x>=8) ----------------
template <int FIRST>
__global__ __launch_bounds__(256) void wo_kl_kernel(const short* __restrict__ A,
                                                    const short* __restrict__ Bt,
                                                    const float* __restrict__ bias,
                                                    short* __restrict__ aout,
                                                    const short* __restrict__ P,
                                                    float* __restrict__ assoc) {
  __shared__ short As[64 * 64];
  __shared__ short Bs[64 * 64];
  const int tid = threadIdx.x;
  const int wid = tid >> 6, lane = tid & 63;
  if (blockIdx.x < 8) {
    const int m0 = blockIdx.y * 64;
    const int n0 = blockIdx.x * 64;
    const int wr = (wid >> 1) * 32;
    const int wc = (wid & 1) * 32;
    f32x4 acc[2][2];
#pragma unroll
    for (int i = 0; i < 2; i++)
#pragma unroll
      for (int j = 0; j < 2; j++)
#pragma unroll
        for (int q = 0; q < 4; q++) acc[i][j][q] = 0.0f;
    const short* aBase = A + (size_t)m0 * 512;
    const short* bBase = Bt + (size_t)n0 * 512;
    const int rowL = lane >> 3;
    const int colE = ((lane & 7) ^ (rowL & 7)) * 8;
    const int g = lane >> 4;
    const int r16 = lane & 15;
    const int rsw = r16 & 7;
    for (int kt = 0; kt < 512; kt += 64) {
      __syncthreads();
#pragma unroll
      for (int c = 0; c < 4; ++c) {
        int s = c * 4 + wid;
        if (s < 8)
          gld_lds16(aBase + (size_t)(s * 8 + rowL) * 512 + kt + colE, As + s * 512);
        else
          gld_lds16(bBase + (size_t)((s - 8) * 8 + rowL) * 512 + kt + colE, Bs + (s - 8) * 512);
      }
      __syncthreads();
      bf16x8 af[2][2], bfr[2][2];
#pragma unroll
      for (int i = 0; i < 2; i++)
#pragma unroll
        for (int kk = 0; kk < 2; kk++)
          af[i][kk] = *(const bf16x8*)&As[(wr + i * 16 + r16) * 64 + (((kk * 4 + g) ^ rsw) * 8)];
#pragma unroll
      for (int j = 0; j < 2; j++)
#pragma unroll
        for (int kk = 0; kk < 2; kk++)
          bfr[j][kk] = *(const bf16x8*)&Bs[(wc + j * 16 + r16) * 64 + (((kk * 4 + g) ^ rsw) * 8)];
#pragma unroll
      for (int kk = 0; kk < 2; kk++)
#pragma unroll
        for (int i = 0; i < 2; i++)
#pragma unroll
          for (int j = 0; j < 2; j++)
            acc[i][j] = __builtin_amdgcn_mfma_f32_16x16x32_bf16(af[i][kk], bfr[j][kk], acc[i][j], 0, 0, 0);
    }
    const int col16 = lane & 15;
    const int rowg = (lane >> 4) * 4;
#pragma unroll
    for (int i = 0; i < 2; i++) {
      int row = m0 + wr + i * 16 + rowg;
#pragma unroll
      for (int j = 0; j < 2; j++) {
        int col = n0 + wc + j * 16 + col16;
        float bv = bias[col];
#pragma unroll
        for (int q = 0; q < 4; q++)
          aout[(size_t)(row + q) * 512 + col] = f2bf(acc[i][j][q] + bv);
      }
    }
  } else {
    const int kb = (blockIdx.x - 8) * 64 + blockIdx.y;
    const int row = kb * 4 + wid;
    const int b = row >> 9, q = row & 511;
    const float prior = 1.0f / 512.0f + 1e-8f;
    float hs[8] = {0.f, 0.f, 0.f, 0.f, 0.f, 0.f, 0.f, 0.f};
#pragma unroll
    for (int h = 0; h < 8; ++h) {
      bf16x8 v = *(const bf16x8*)&P[(((size_t)(b * 8 + h)) * 512 + q) * 512 + lane * 8];
#pragma unroll
      for (int k = 0; k < 8; ++k) hs[k] += bf2f((unsigned short)v[k]);
    }
    float s = 0.f;
#pragma unroll
    for (int k = 0; k < 8; ++k) {
      float a = hs[k] * 0.125f + 1e-8f;
      s += a * __logf(a / prior);
    }
#pragma unroll
    for (int m = 32; m; m >>= 1) s += __shfl_xor(s, m, 64);
    if (lane == 0) assoc[row] = FIRST ? s : (assoc[row] + s);
  }
}

// ---------------- layernorm in-place on bf16 residual stream ----------------
__global__ __launch_bounds__(256) void ln_kernel(const short* __restrict__ res,
                                                 const float* __restrict__ g,
                                                 const float* __restrict__ bta,
                                                 short* __restrict__ hbf) {
  const int wid = threadIdx.x >> 6, lane = threadIdx.x & 63;
  const size_t row = (size_t)blockIdx.x * 4 + wid;
  bf16x8 hv = *(const bf16x8*)&hbf[row * 512 + lane * 8];
  bf16x8 rv = *(const bf16x8*)&res[row * 512 + lane * 8];
  float v[8], s = 0.f, s2 = 0.f;
#pragma unroll
  for (int i = 0; i < 8; i++) {
    v[i] = bf2f((unsigned short)hv[i]) + bf2f((unsigned short)rv[i]);
    s += v[i];
    s2 += v[i] * v[i];
  }
#pragma unroll
  for (int m = 32; m; m >>= 1) {
    s += __shfl_xor(s, m, 64);
    s2 += __shfl_xor(s2, m, 64);
  }
  float mu = s * (1.0f / 512.0f);
  float var = s2 * (1.0f / 512.0f) - mu * mu;
  float rs = rsqrtf(var + 1e-5f);
  const float* gp = g + lane * 8;
  const float* bp = bta + lane * 8;
  bf16x8 ob;
#pragma unroll
  for (int i = 0; i < 8; i++) ob[i] = f2bf((v[i] - mu) * rs * gp[i] + bp[i]);
  *(bf16x8*)&hbf[row * 512 + lane * 8] = ob;
}

// ---------------- tail union: score1 GEMM (x<2) + recon MFMA (x==2) ----------------
__global__ __launch_bounds__(256) void tail_kernel(const short* __restrict__ hbf,
                                                   const short* __restrict__ ws1t,
                                                   const float* __restrict__ bs1,
                                                   short* __restrict__ sc1,
                                                   const short* __restrict__ WoutT,
                                                   const float* __restrict__ bout,
                                                   float* __restrict__ out) {
  __shared__ short As[128 * 64];
  __shared__ short Bs[128 * 64];
  const int tid = threadIdx.x;
  const int wid = tid >> 6, lane = tid & 63;
  const int g = lane >> 4, r16 = lane & 15;
  if (blockIdx.x < 2) {
    const int m0 = blockIdx.y * 128;
    const int n0 = blockIdx.x * 128;
    const int wr = (wid >> 1) * 64;
    const int wc = (wid & 1) * 64;
    f32x4 acc[4][4];
#pragma unroll
    for (int i = 0; i < 4; i++)
#pragma unroll
      for (int j = 0; j < 4; j++)
#pragma unroll
        for (int q = 0; q < 4; q++) acc[i][j][q] = 0.0f;
    const short* aBase = hbf + (size_t)m0 * 512;
    const short* bBase = ws1t + (size_t)n0 * 512;
    const int rowL = lane >> 3;
    const int colE = ((lane & 7) ^ (rowL & 7)) * 8;
    const int rsw = r16 & 7;
    for (int kt = 0; kt < 512; kt += 64) {
      __syncthreads();
#pragma unroll
      for (int c = 0; c < 8; ++c) {
        int s = c * 4 + wid;
        if (s < 16)
          gld_lds16(aBase + (size_t)(s * 8 + rowL) * 512 + kt + colE, As + s * 512);
        else
          gld_lds16(bBase + (size_t)((s - 16) * 8 + rowL) * 512 + kt + colE, Bs + (s - 16) * 512);
      }
      __syncthreads();
      bf16x8 af[4][2], bfr[4][2];
#pragma unroll
      for (int i = 0; i < 4; i++)
#pragma unroll
        for (int kk = 0; kk < 2; kk++)
          af[i][kk] = *(const bf16x8*)&As[(wr + i * 16 + r16) * 64 + (((kk * 4 + g) ^ rsw) * 8)];
#pragma unroll
      for (int j = 0; j < 4; j++)
#pragma unroll
        for (int kk = 0; kk < 2; kk++)
          bfr[j][kk] = *(const bf16x8*)&Bs[(wc + j * 16 + r16) * 64 + (((kk * 4 + g) ^ rsw) * 8)];
#pragma unroll
      for (int kk = 0; kk < 2; kk++)
#pragma unroll
        for (int i = 0; i < 4; i++)
#pragma unroll
          for (int j = 0; j < 4; j++)
            acc[i][j] = __builtin_amdgcn_mfma_f32_16x16x32_bf16(af[i][kk], bfr[j][kk], acc[i][j], 0, 0, 0);
    }
    const int rowg = g * 4;
#pragma unroll
    for (int i = 0; i < 4; i++) {
      int row = m0 + wr + i * 16 + rowg;
#pragma unroll
      for (int j = 0; j < 4; j++) {
        int col = n0 + wc + j * 16 + r16;
        float bv = bs1[col];
#pragma unroll
        for (int q = 0; q < 4; q++)
          sc1[(size_t)(row + q) * 256 + col] = f2bf(fmaxf(acc[i][j][q] + bv, 0.0f));
      }
    }
  } else {
    const int wbase = blockIdx.y * 128 + wid * 32;
    const int kg = g * 8;
    f32x4 acc[2][2];
#pragma unroll
    for (int i = 0; i < 2; i++)
#pragma unroll
      for (int j = 0; j < 2; j++)
#pragma unroll
        for (int q = 0; q < 4; q++) acc[i][j][q] = 0.0f;
    for (int kt = 0; kt < 512; kt += 32) {
      bf16x8 af[2], bfr[2];
#pragma unroll
      for (int i = 0; i < 2; i++)
        af[i] = *(const bf16x8*)&hbf[(size_t)(wbase + i * 16 + r16) * 512 + kt + kg];
#pragma unroll
      for (int j = 0; j < 2; j++)
        bfr[j] = *(const bf16x8*)&WoutT[(size_t)(j * 16 + r16) * 512 + kt + kg];
#pragma unroll
      for (int i = 0; i < 2; i++)
#pragma unroll
        for (int j = 0; j < 2; j++)
          acc[i][j] = __builtin_amdgcn_mfma_f32_16x16x32_bf16(af[i], bfr[j], acc[i][j], 0, 0, 0);
    }
    const int rowg = g * 4;
#pragma unroll
    for (int i = 0; i < 2; i++)
#pragma unroll
      for (int j = 0; j < 2; j++) {
        int col = j * 16 + r16;
#pragma unroll
        for (int q = 0; q < 4; q++)
          out[(size_t)(wbase + i * 16 + rowg + q) * 32 + col] = acc[i][j][q] + bout[col];
      }
  }
}

// ---------------- score stage 2 + assoc output ----------------
__global__ __launch_bounds__(256) void score2_kernel(const short* __restrict__ s1,
                                                     const float* __restrict__ Ws2,
                                                     const float* __restrict__ bs2,
                                                     const float* __restrict__ assoc,
                                                     float* __restrict__ outScore,
                                                     float* __restrict__ outAssoc) {
  const int wid = threadIdx.x >> 6, lane = threadIdx.x & 63;
  const int row = blockIdx.x * 4 + wid;
  const short* rp = &s1[(size_t)row * 256 + lane * 4];
  float d = 0.f;
#pragma unroll
  for (int e = 0; e < 4; e++) d += bf2f((unsigned short)rp[e]) * Ws2[lane * 4 + e];
#pragma unroll
  for (int m = 32; m; m >>= 1) d += __shfl_xor(d, m, 64);
  if (lane == 0) {
    outScore[row] = 1.f / (1.f + __expf(-(d + bs2[0])));
    outAssoc[row] = assoc[row] * (1.0f / 6.0f);
  }
}

extern "C" void kernel_launch(void* const* d_in, const int* in_sizes, int n_in,
                              void* d_out, int out_size, void* d_ws, size_t ws_size,
                              hipStream_t stream) {
  const float* x    = (const float*)d_in[0];
  const float* W_in = (const float*)d_in[1];
  const float* b_in = (const float*)d_in[2];
  const float* pe   = (const float*)d_in[3];
  const float* Wq   = (const float*)d_in[4];
  const float* Wk   = (const float*)d_in[5];
  const float* Wv   = (const float*)d_in[6];
  const float* Wo   = (const float*)d_in[7];
  const float* bo   = (const float*)d_in[8];
  const float* W1   = (const float*)d_in[9];
  const float* b1   = (const float*)d_in[10];
  const float* W2   = (const float*)d_in[11];
  const float* b2   = (const float*)d_in[12];
  const float* ln1g = (const float*)d_in[13];
  const float* ln1b = (const float*)d_in[14];
  const float* ln2g = (const float*)d_in[15];
  const float* ln2b = (const float*)d_in[16];
  const float* Wout = (const float*)d_in[17];
  const float* bout = (const float*)d_in[18];
  const float* Ws1  = (const float*)d_in[19];
  const float* bs1  = (const float*)d_in[20];
  const float* Ws2  = (const float*)d_in[21];
  const float* bs2  = (const float*)d_in[22];

  char* p = (char*)d_ws;
  auto alloc = [&](size_t bytes) {
    void* r = (void*)p;
    p += (bytes + 255) & ~(size_t)255;
    return r;
  };
  short* h_bf  = (short*)alloc((size_t)4096 * 512 * 2);
  short* qh    = (short*)alloc((size_t)4096 * 1536 * 2);
  short* aout  = (short*)alloc((size_t)4096 * 512 * 2);
  short* ctxb  = (short*)alloc((size_t)4096 * 512 * 2);
  short* ff1b  = (short*)alloc((size_t)4096 * 2048 * 2);
  short* ff2   = (short*)alloc((size_t)4096 * 512 * 2);
  float* assoc = (float*)alloc((size_t)4096 * 4);
  short* Pbuf  = (short*)alloc((size_t)64 * 512 * 512 * 2);
  short* Vt    = (short*)alloc((size_t)64 * 64 * 512 * 2);
  short* sc1   = (short*)alloc((size_t)4096 * 256 * 2);
  short* qkvt  = (short*)alloc((size_t)6 * 1536 * 512 * 2);
  short* wot   = (short*)alloc((size_t)6 * 512 * 512 * 2);
  short* w1t   = (short*)alloc((size_t)6 * 2048 * 512 * 2);
  short* w2t   = (short*)alloc((size_t)6 * 512 * 2048 * 2);
  short* ws1t  = (short*)alloc((size_t)256 * 512 * 2);
  short* woutT = (short*)alloc((size_t)32 * 512 * 2);

  prologue_kernel<<<26768, 256, 0, stream>>>(x, W_in, b_in, pe, h_bf, Wq, Wk, Wv, Wo, W1, W2,
                                             Ws1, Wout, qkvt, wot, w1t, w2t, ws1t, woutT);

  for (int l = 0; l < 6; ++l) {
    gemm_bt<5, 128, 128, 64><<<dim3(12, 32), 256, 0, stream>>>(
        h_bf, qkvt + (size_t)l * 786432, qh, nullptr, 4096, 1536, 512);
    vt_kernel<<<dim3(16, 2, 64), 256, 0, stream>>>(qh, Vt);
    smpv_kernel<<<2048, 256, 0, stream>>>(qh, Vt, Pbuf, ctxb);
    if (l == 0)
      wo_kl_kernel<1><<<dim3(24, 64), 256, 0, stream>>>(ctxb, wot + (size_t)l * 262144,
                                                        bo + l * 512, aout, Pbuf, assoc);
    else
      wo_kl_kernel<0><<<dim3(24, 64), 256, 0, stream>>>(ctxb, wot + (size_t)l * 262144,
                                                        bo + l * 512, aout, Pbuf, assoc);
    ln_kernel<<<1024, 256, 0, stream>>>(aout, ln1g + l * 512, ln1b + l * 512, h_bf);
    gemm_bt<2, 128, 128, 64><<<dim3(16, 32), 256, 0, stream>>>(
        h_bf, w1t + (size_t)l * 1048576, ff1b, b1 + l * 2048, 4096, 2048, 512);
    gemm_bt<4, 64, 64, 64><<<dim3(8, 64), 256, 0, stream>>>(
        ff1b, w2t + (size_t)l * 1048576, ff2, b2 + l * 512, 4096, 512, 2048);
    ln_kernel<<<1024, 256, 0, stream>>>(ff2, ln2g + l * 512, ln2b + l * 512, h_bf);
  }

  float* out = (float*)d_out;
  tail_kernel<<<dim3(3, 32), 256, 0, stream>>>(h_bf, ws1t, bs1, sc1, woutT, bout, out);
  score2_kernel<<<1024, 256, 0, stream>>>(sc1, Ws2, bs2, assoc, out + 131072,
                                          out + 131072 + 4096);
}